// Round 12
// baseline (915.744 us; speedup 1.0000x reference)
//
#include <hip/hip_runtime.h>
#include <hip/hip_bf16.h>
#include <stdint.h>

// Problem constants (B=16, C=256, NH=4, D=64, G=32, L=HW=1024)
// Round 12: OUTPUT IS FLOAT32. The R0 assumption "harness reads d_out as
// bf16" came from misreading traceback source-context (all dtype branches
// are printed; none is marked executed). With f32 output, every prior result
// is explained exactly: bf16 writes packed two values per f32 slot, so the
// harness read f32 word i ~= my_out[2i+1] -> sqrt(2)-decorrelated absmax
// ~7.3, bit-identical across different implementations (bf16 quantization
// crushed their tiny differences); R10 echo -> 7.0 (x[2i+1] + zero tail);
// R5 bf16-reads -> NaN; R7 detector -> inputs genuinely f32; threshold
// 0.104375 == 2% * 5.21875 (f32 path, floor_eps_k=None).
// Pipeline (cross-validated tiled version, NCHW, dict input order):
//   stats_kernel : per (b,group) mean/rsqrt -> stats[512] float2
//   gemm_qkv     : GN folded into B-tile load; qkv[b,768,L] bf16 (24 MB ws)
//   attn_kernel  : per (b,head,8 q-rows): S in LDS, softmax, P@V -> o bf16
//   gemm_proj    : out = wproj @ o + bproj + x -> FLOAT32 d_out
// ws ~33.6 MB guarded; per-batch fallback (~2.2 MB) if ws_size smaller.

typedef __hip_bfloat16 bf16;

__global__ __launch_bounds__(256) void stats_kernel(const float* __restrict__ x,
    float2* __restrict__ stats) {
  int b = blockIdx.x >> 5, g = blockIdx.x & 31;
  const float* xp = x + (size_t)(b * 256 + g * 8) * 1024;
  float s = 0.f, ss = 0.f;
  for (int i = threadIdx.x; i < 8192; i += 256) {
    float v = xp[i]; s += v; ss += v * v;
  }
  #pragma unroll
  for (int o = 32; o; o >>= 1) { s += __shfl_down(s, o); ss += __shfl_down(ss, o); }
  __shared__ float red[2][4];
  int wid = threadIdx.x >> 6;
  if ((threadIdx.x & 63) == 0) { red[0][wid] = s; red[1][wid] = ss; }
  __syncthreads();
  if (threadIdx.x == 0) {
    s  = red[0][0] + red[0][1] + red[0][2] + red[0][3];
    ss = red[1][0] + red[1][1] + red[1][2] + red[1][3];
    float mean = s * (1.f / 8192.f);
    float var  = ss * (1.f / 8192.f) - mean * mean;
    stats[blockIdx.x] = make_float2(mean, rsqrtf(var + 1e-5f));
  }
}

// qkv[b][m][l] = sum_c W[m][c] * GN(x)[b][c][l] + bias[m], bf16 out.
__global__ __launch_bounds__(256) void gemm_qkv(
    const float* __restrict__ x, const float* __restrict__ gamma,
    const float* __restrict__ beta, const float2* __restrict__ stats,
    const float* __restrict__ wq, const float* __restrict__ bq,
    const float* __restrict__ wk, const float* __restrict__ bk,
    const float* __restrict__ wv, const float* __restrict__ bv,
    bf16* __restrict__ qkv, int b_off, size_t qkv_bstride) {
  __shared__ float As[16][65];
  __shared__ float Bs[16][65];
  int zb = blockIdx.z;
  int b  = zb + b_off;
  int m0 = blockIdx.y * 64, l0 = blockIdx.x * 64;
  int sec = m0 >> 8;
  const float* W  = (sec == 0) ? wq : (sec == 1) ? wk : wv;
  const float* bi = (sec == 0) ? bq : (sec == 1) ? bk : bv;
  int rr0 = m0 & 255;
  const float*  xb = x + (size_t)b * 256 * 1024;
  const float2* st = stats + b * 32;
  int tid = threadIdx.x;
  int tx = tid & 15, ty = tid >> 4;
  float acc[4][4] = {};
  for (int k0 = 0; k0 < 256; k0 += 16) {
    for (int i = tid; i < 1024; i += 256) {
      int k = i >> 6, mm = i & 63;
      As[k][mm] = W[(size_t)(rr0 + mm) * 256 + k0 + k];
      int c = k0 + k;
      float2 s2 = st[c >> 3];
      Bs[k][mm] = (xb[(size_t)c * 1024 + l0 + mm] - s2.x) * s2.y * gamma[c] + beta[c];
    }
    __syncthreads();
    #pragma unroll
    for (int k = 0; k < 16; k++) {
      float a[4], bb[4];
      #pragma unroll
      for (int i = 0; i < 4; i++) a[i] = As[k][ty * 4 + i];
      #pragma unroll
      for (int j = 0; j < 4; j++) bb[j] = Bs[k][tx * 4 + j];
      #pragma unroll
      for (int i = 0; i < 4; i++)
        #pragma unroll
        for (int j = 0; j < 4; j++) acc[i][j] += a[i] * bb[j];
    }
    __syncthreads();
  }
  bf16* Cp = qkv + (size_t)zb * qkv_bstride;
  #pragma unroll
  for (int i = 0; i < 4; i++) {
    float bv_ = bi[rr0 + ty * 4 + i];
    #pragma unroll
    for (int j = 0; j < 4; j++)
      Cp[(size_t)(m0 + ty * 4 + i) * 1024 + l0 + tx * 4 + j] =
          __float2bfloat16(acc[i][j] + bv_);
  }
}

// One block per (b, head, 8-row q tile). qkv/o are bf16 ws buffers (ours).
__global__ __launch_bounds__(256) void attn_kernel(
    const bf16* __restrict__ qkv, bf16* __restrict__ o,
    size_t qkv_bstride, size_t o_bstride) {
  __shared__ float Qs[64][8];
  __shared__ float Ss[8][1025];
  int zb = blockIdx.z, n = blockIdx.y;
  int q0 = blockIdx.x * 8;
  const bf16* Qp = qkv + (size_t)zb * qkv_bstride + (size_t)(n * 64) * 1024;
  const bf16* Kp = Qp + (size_t)256 * 1024;
  const bf16* Vp = Qp + (size_t)512 * 1024;
  int tid = threadIdx.x;

  for (int i = tid; i < 512; i += 256) {
    int d = i >> 3, qi = i & 7;
    Qs[d][qi] = __bfloat162float(Qp[d * 1024 + q0 + qi]);
  }
  __syncthreads();

  // S[qi][m] = 0.125 * sum_d Q[d][qi] * K[d][m]
  for (int mc = 0; mc < 4; mc++) {
    int m = mc * 256 + tid;
    float acc[8] = {};
    for (int d = 0; d < 64; d++) {
      float kv = __bfloat162float(Kp[d * 1024 + m]);
      #pragma unroll
      for (int qi = 0; qi < 8; qi++) acc[qi] += Qs[d][qi] * kv;
    }
    #pragma unroll
    for (int qi = 0; qi < 8; qi++) Ss[qi][m] = acc[qi] * 0.125f;
  }
  __syncthreads();

  // softmax over m, one 32-lane group per row
  {
    int r = tid >> 5, j = tid & 31;
    float mx = -1e30f;
    for (int m = j; m < 1024; m += 32) mx = fmaxf(mx, Ss[r][m]);
    #pragma unroll
    for (int off = 16; off; off >>= 1) mx = fmaxf(mx, __shfl_xor(mx, off, 32));
    float sum = 0.f;
    for (int m = j; m < 1024; m += 32) {
      float e = __expf(Ss[r][m] - mx);
      Ss[r][m] = e;
      sum += e;
    }
    #pragma unroll
    for (int off = 16; off; off >>= 1) sum += __shfl_xor(sum, off, 32);
    float inv = 1.f / sum;
    for (int m = j; m < 1024; m += 32) Ss[r][m] *= inv;
  }
  __syncthreads();

  // O[d][qi] = sum_m P[qi][m] * V[d][m]; qi = tid&7, d = (tid>>3)*2 + t
  int qi = tid & 7, dg = tid >> 3;
  float acc[2] = {0.f, 0.f};
  #pragma unroll 4
  for (int m = 0; m < 1024; m++) {
    float p = Ss[qi][m];
    #pragma unroll
    for (int t = 0; t < 2; t++)
      acc[t] += p * __bfloat162float(Vp[(dg * 2 + t) * 1024 + m]);
  }
  bf16* op = o + (size_t)zb * o_bstride + (size_t)(n * 64) * 1024 + q0;
  #pragma unroll
  for (int t = 0; t < 2; t++)
    op[(dg * 2 + t) * 1024 + qi] = __float2bfloat16(acc[t]);
}

// out[b][c][l] = sum_e wproj[c][e]*o[e][l] + bproj[c] + x[b][c][l] -> FLOAT32
__global__ __launch_bounds__(256) void gemm_proj(const float* __restrict__ A,
    const bf16* __restrict__ o, const float* __restrict__ bias,
    const float* __restrict__ x, float* __restrict__ out,
    int b_off, size_t o_bstride) {
  __shared__ float As[16][65];
  __shared__ float Bs[16][65];
  int zb = blockIdx.z;
  int b  = zb + b_off;
  int m0 = blockIdx.y * 64, l0 = blockIdx.x * 64;
  const bf16* op = o + (size_t)zb * o_bstride;
  int tid = threadIdx.x;
  int tx = tid & 15, ty = tid >> 4;
  float acc[4][4] = {};
  for (int k0 = 0; k0 < 256; k0 += 16) {
    for (int i = tid; i < 1024; i += 256) {
      int k = i >> 6, mm = i & 63;
      As[k][mm] = A[(size_t)(m0 + mm) * 256 + k0 + k];
      Bs[k][mm] = __bfloat162float(op[(size_t)(k0 + k) * 1024 + l0 + mm]);
    }
    __syncthreads();
    #pragma unroll
    for (int k = 0; k < 16; k++) {
      float a[4], bb[4];
      #pragma unroll
      for (int i = 0; i < 4; i++) a[i] = As[k][ty * 4 + i];
      #pragma unroll
      for (int j = 0; j < 4; j++) bb[j] = Bs[k][tx * 4 + j];
      #pragma unroll
      for (int i = 0; i < 4; i++)
        #pragma unroll
        for (int j = 0; j < 4; j++) acc[i][j] += a[i] * bb[j];
    }
    __syncthreads();
  }
  #pragma unroll
  for (int i = 0; i < 4; i++) {
    int m = m0 + ty * 4 + i;
    float bv_ = bias[m];
    #pragma unroll
    for (int j = 0; j < 4; j++) {
      size_t idx = (size_t)(b * 256 + m) * 1024 + l0 + tx * 4 + j;
      out[idx] = acc[i][j] + bv_ + x[idx];       // f32 store
    }
  }
}

extern "C" void kernel_launch(void* const* d_in, const int* in_sizes, int n_in,
                              void* d_out, int out_size, void* d_ws, size_t ws_size,
                              hipStream_t stream) {
  // input-order resolver (R9 proved dict order; kept as cheap insurance)
  int ix = 0, iga = 1, ibe = 2, iwq = 3, ibq = 4, iwk = 5, ibk = 6,
      iwv = 7, ibv = 8, iwp = 9, ibp = 10;
  if (in_sizes[0] != 4194304) {
    if (in_sizes[10] == 4194304 && in_sizes[1] == 256) {
      ibe = 0; ibk = 1; ibp = 2; ibq = 3; ibv = 4; iga = 5;
      iwk = 6; iwp = 7; iwq = 8; iwv = 9; ix = 10;
    } else if (in_sizes[10] == 4194304 && in_sizes[1] == 65536) {
      ibp = 0; iwp = 1; ibv = 2; iwv = 3; ibk = 4; iwk = 5;
      ibq = 6; iwq = 7; ibe = 8; iga = 9; ix = 10;
    } else {
      for (int i = 0; i < 11; i++) if (in_sizes[i] == 4194304) ix = i;
    }
  }
  const float* x     = (const float*)d_in[ix];
  const float* gamma = (const float*)d_in[iga];
  const float* beta  = (const float*)d_in[ibe];
  const float* wq    = (const float*)d_in[iwq];
  const float* bq    = (const float*)d_in[ibq];
  const float* wk    = (const float*)d_in[iwk];
  const float* bk    = (const float*)d_in[ibk];
  const float* wv    = (const float*)d_in[iwv];
  const float* bv    = (const float*)d_in[ibv];
  const float* wproj = (const float*)d_in[iwp];
  const float* bproj = (const float*)d_in[ibp];
  float* out = (float*)d_out;                       // FLOAT32 output

  const size_t QKV_B = (size_t)768 * 1024;
  const size_t O_B   = (size_t)256 * 1024;
  char* wsp = (char*)d_ws;
  float2* stats = (float2*)wsp;              // 4 KB
  const size_t DATA0 = 8192;
  size_t full_need = DATA0 + 16 * QKV_B * 2 + 16 * O_B * 2;   // ~33.6 MB

  stats_kernel<<<512, 256, 0, stream>>>(x, stats);

  if (ws_size >= full_need) {
    bf16* qkv = (bf16*)(wsp + DATA0);
    bf16* o   = (bf16*)(wsp + DATA0 + 16 * QKV_B * 2);
    gemm_qkv <<<dim3(16, 12, 16), 256, 0, stream>>>(x, gamma, beta, stats,
        wq, bq, wk, bk, wv, bv, qkv, 0, QKV_B);
    attn_kernel<<<dim3(128, 4, 16), 256, 0, stream>>>(qkv, o, QKV_B, O_B);
    gemm_proj<<<dim3(16, 4, 16), 256, 0, stream>>>(wproj, o, bproj, x, out,
        0, O_B);
  } else {
    bf16* qkv = (bf16*)(wsp + DATA0);
    bf16* o   = (bf16*)(wsp + DATA0 + QKV_B * 2);
    for (int b = 0; b < 16; b++) {
      gemm_qkv <<<dim3(16, 12, 1), 256, 0, stream>>>(x, gamma, beta, stats,
          wq, bq, wk, bk, wv, bv, qkv, b, 0);
      attn_kernel<<<dim3(128, 4, 1), 256, 0, stream>>>(qkv, o, 0, 0);
      gemm_proj<<<dim3(16, 4, 1), 256, 0, stream>>>(wproj, o, bproj, x, out,
          b, 0);
    }
  }
}

// Round 13
// 469.002 us; speedup vs baseline: 1.9525x; 1.9525x over previous
//
#include <hip/hip_runtime.h>
#include <hip/hip_bf16.h>
#include <stdint.h>

// Problem constants (B=16, C=256, NH=4, D=64, G=32, L=HW=1024)
// Round 13: MFMA attention. R12 PASSED (915.7 us, absmax 0.031); profile:
// attn_kernel = 694 us (76%), MfmaUtil=0, VALUBusy=50%, HBM=2% -> vector-pipe
// bound at 24.8 TF while the 2.5 PF matrix pipe idles. This round rewrites
// ONLY attn_kernel on v_mfma_f32_16x16x32_bf16 (verified layouts: A[m=lane&15]
// [k=quad*8+j]; B[k=quad*8+j][n=lane&15]; D[row=quad*4+reg][col=lane&15]).
// Per block (b, head, 16 q-rows): Q^T,K^T staged in LDS (68-pad rows, b64
// frag reads, 2-way-free banks), S=QK^T*0.125 -> bf16 S[16][1028] in LDS,
// full-row softmax, PV with B-frags as dwordx4 global V loads, scale by 1/sum.
// stats/gemm_qkv/gemm_proj unchanged from the passing R12 kernel.

typedef __hip_bfloat16 bf16;
typedef __attribute__((ext_vector_type(8))) short short8;
typedef __attribute__((ext_vector_type(4))) float float4v;

__global__ __launch_bounds__(256) void stats_kernel(const float* __restrict__ x,
    float2* __restrict__ stats) {
  int b = blockIdx.x >> 5, g = blockIdx.x & 31;
  const float* xp = x + (size_t)(b * 256 + g * 8) * 1024;
  float s = 0.f, ss = 0.f;
  for (int i = threadIdx.x; i < 8192; i += 256) {
    float v = xp[i]; s += v; ss += v * v;
  }
  #pragma unroll
  for (int o = 32; o; o >>= 1) { s += __shfl_down(s, o); ss += __shfl_down(ss, o); }
  __shared__ float red[2][4];
  int wid = threadIdx.x >> 6;
  if ((threadIdx.x & 63) == 0) { red[0][wid] = s; red[1][wid] = ss; }
  __syncthreads();
  if (threadIdx.x == 0) {
    s  = red[0][0] + red[0][1] + red[0][2] + red[0][3];
    ss = red[1][0] + red[1][1] + red[1][2] + red[1][3];
    float mean = s * (1.f / 8192.f);
    float var  = ss * (1.f / 8192.f) - mean * mean;
    stats[blockIdx.x] = make_float2(mean, rsqrtf(var + 1e-5f));
  }
}

// qkv[b][m][l] = sum_c W[m][c] * GN(x)[b][c][l] + bias[m], bf16 out.
__global__ __launch_bounds__(256) void gemm_qkv(
    const float* __restrict__ x, const float* __restrict__ gamma,
    const float* __restrict__ beta, const float2* __restrict__ stats,
    const float* __restrict__ wq, const float* __restrict__ bq,
    const float* __restrict__ wk, const float* __restrict__ bk,
    const float* __restrict__ wv, const float* __restrict__ bv,
    bf16* __restrict__ qkv, int b_off, size_t qkv_bstride) {
  __shared__ float As[16][65];
  __shared__ float Bs[16][65];
  int zb = blockIdx.z;
  int b  = zb + b_off;
  int m0 = blockIdx.y * 64, l0 = blockIdx.x * 64;
  int sec = m0 >> 8;
  const float* W  = (sec == 0) ? wq : (sec == 1) ? wk : wv;
  const float* bi = (sec == 0) ? bq : (sec == 1) ? bk : bv;
  int rr0 = m0 & 255;
  const float*  xb = x + (size_t)b * 256 * 1024;
  const float2* st = stats + b * 32;
  int tid = threadIdx.x;
  int tx = tid & 15, ty = tid >> 4;
  float acc[4][4] = {};
  for (int k0 = 0; k0 < 256; k0 += 16) {
    for (int i = tid; i < 1024; i += 256) {
      int k = i >> 6, mm = i & 63;
      As[k][mm] = W[(size_t)(rr0 + mm) * 256 + k0 + k];
      int c = k0 + k;
      float2 s2 = st[c >> 3];
      Bs[k][mm] = (xb[(size_t)c * 1024 + l0 + mm] - s2.x) * s2.y * gamma[c] + beta[c];
    }
    __syncthreads();
    #pragma unroll
    for (int k = 0; k < 16; k++) {
      float a[4], bb[4];
      #pragma unroll
      for (int i = 0; i < 4; i++) a[i] = As[k][ty * 4 + i];
      #pragma unroll
      for (int j = 0; j < 4; j++) bb[j] = Bs[k][tx * 4 + j];
      #pragma unroll
      for (int i = 0; i < 4; i++)
        #pragma unroll
        for (int j = 0; j < 4; j++) acc[i][j] += a[i] * bb[j];
    }
    __syncthreads();
  }
  bf16* Cp = qkv + (size_t)zb * qkv_bstride;
  #pragma unroll
  for (int i = 0; i < 4; i++) {
    float bv_ = bi[rr0 + ty * 4 + i];
    #pragma unroll
    for (int j = 0; j < 4; j++)
      Cp[(size_t)(m0 + ty * 4 + i) * 1024 + l0 + tx * 4 + j] =
          __float2bfloat16(acc[i][j] + bv_);
  }
}

// MFMA attention: one block per (b, head, 16-row q tile).
__global__ __launch_bounds__(256) void attn_kernel(
    const bf16* __restrict__ qkv, bf16* __restrict__ o,
    size_t qkv_bstride, size_t o_bstride) {
  __shared__ bf16 Qa[16][68];      // [qi][d] (Q^T); row 136 B: b64-aligned, 2-way banks
  __shared__ bf16 Kt[128][68];     // [m][d]  (K^T chunk)
  __shared__ bf16 S[16][1028];     // scores -> P (bf16); row 2056 B
  __shared__ float invs[16];

  int zb = blockIdx.z, n = blockIdx.y;
  int q0 = blockIdx.x * 16;
  const bf16* Qp = qkv + (size_t)zb * qkv_bstride + (size_t)(n * 64) * 1024;
  const bf16* Kp = Qp + (size_t)256 * 1024;
  const bf16* Vp = Qp + (size_t)512 * 1024;
  int tid = threadIdx.x;
  int lane = tid & 63, wave = tid >> 6;
  int l16 = lane & 15, quad = lane >> 4;

  // stage Q transposed: Qa[qi][d] = Q[d][q0+qi]
  for (int i = tid; i < 1024; i += 256) {
    int d = i >> 4, qi = i & 15;
    Qa[qi][d] = Qp[(size_t)d * 1024 + q0 + qi];
  }

  // ---- S phase: 8 chunks of 128 key-columns ----
  for (int mc = 0; mc < 8; mc++) {
    __syncthreads();   // Kt reusable (also covers Qa on first pass)
    for (int i = tid; i < 4096; i += 256) {   // Kt[m][d] = K[d][mc*128+m], d-pairs
      int m = i & 127, dp = (i >> 7) * 2;
      uint32_t v0 = (uint32_t)*(const uint16_t*)&Kp[(size_t)dp * 1024 + mc * 128 + m];
      uint32_t v1 = (uint32_t)*(const uint16_t*)&Kp[(size_t)(dp + 1) * 1024 + mc * 128 + m];
      *(uint32_t*)&Kt[m][dp] = v0 | (v1 << 16);
    }
    __syncthreads();
    #pragma unroll
    for (int s = 0; s < 2; s++) {           // each wave: 2 column-subtiles
      int st = wave * 2 + s;
      float4v acc = {0.f, 0.f, 0.f, 0.f};
      #pragma unroll
      for (int h = 0; h < 2; h++) {          // k-dim 64 = 2 x 32
        short8 af = *(const short8*)&Qa[l16][h * 32 + quad * 8];
        short8 bf = *(const short8*)&Kt[st * 16 + l16][h * 32 + quad * 8];
        acc = __builtin_amdgcn_mfma_f32_16x16x32_bf16(af, bf, acc, 0, 0, 0);
      }
      #pragma unroll
      for (int r = 0; r < 4; r++)            // D[row=quad*4+r][col=l16]
        S[quad * 4 + r][mc * 128 + st * 16 + l16] =
            __float2bfloat16(acc[r] * 0.125f);
    }
  }
  __syncthreads();

  // ---- softmax: 16 lanes per row ----
  {
    int r = tid >> 4, j = tid & 15;
    float mx = -1e30f;
    for (int m = j; m < 1024; m += 16)
      mx = fmaxf(mx, __bfloat162float(S[r][m]));
    #pragma unroll
    for (int off = 8; off; off >>= 1) mx = fmaxf(mx, __shfl_xor(mx, off, 16));
    float sum = 0.f;
    for (int m = j; m < 1024; m += 16) {
      float e = __expf(__bfloat162float(S[r][m]) - mx);
      S[r][m] = __float2bfloat16(e);
      sum += e;
    }
    #pragma unroll
    for (int off = 8; off; off >>= 1) sum += __shfl_xor(sum, off, 16);
    if (j == 0) invs[r] = 1.f / sum;
  }
  __syncthreads();

  // ---- PV: wave w -> d-tile [w*16, w*16+16) ; K-dim 1024 = 32 x 32 ----
  {
    int d0 = wave * 16;
    float4v acc = {0.f, 0.f, 0.f, 0.f};
    const bf16* vrow = Vp + (size_t)(d0 + l16) * 1024 + quad * 8;
    for (int kt = 0; kt < 32; kt++) {
      short8 af = *(const short8*)&S[l16][kt * 32 + quad * 8];
      short8 bf = *(const short8*)(vrow + kt * 32);   // 16B global load
      acc = __builtin_amdgcn_mfma_f32_16x16x32_bf16(af, bf, acc, 0, 0, 0);
    }
    bf16* op = o + (size_t)zb * o_bstride + (size_t)(n * 64 + d0 + l16) * 1024 + q0;
    #pragma unroll
    for (int r = 0; r < 4; r++) {
      int qi = quad * 4 + r;                 // D[row=qi][col=d]
      op[qi] = __float2bfloat16(acc[r] * invs[qi]);
    }
  }
}

// out[b][c][l] = sum_e wproj[c][e]*o[e][l] + bproj[c] + x[b][c][l] -> FLOAT32
__global__ __launch_bounds__(256) void gemm_proj(const float* __restrict__ A,
    const bf16* __restrict__ o, const float* __restrict__ bias,
    const float* __restrict__ x, float* __restrict__ out,
    int b_off, size_t o_bstride) {
  __shared__ float As[16][65];
  __shared__ float Bs[16][65];
  int zb = blockIdx.z;
  int b  = zb + b_off;
  int m0 = blockIdx.y * 64, l0 = blockIdx.x * 64;
  const bf16* op = o + (size_t)zb * o_bstride;
  int tid = threadIdx.x;
  int tx = tid & 15, ty = tid >> 4;
  float acc[4][4] = {};
  for (int k0 = 0; k0 < 256; k0 += 16) {
    for (int i = tid; i < 1024; i += 256) {
      int k = i >> 6, mm = i & 63;
      As[k][mm] = A[(size_t)(m0 + mm) * 256 + k0 + k];
      Bs[k][mm] = __bfloat162float(op[(size_t)(k0 + k) * 1024 + l0 + mm]);
    }
    __syncthreads();
    #pragma unroll
    for (int k = 0; k < 16; k++) {
      float a[4], bb[4];
      #pragma unroll
      for (int i = 0; i < 4; i++) a[i] = As[k][ty * 4 + i];
      #pragma unroll
      for (int j = 0; j < 4; j++) bb[j] = Bs[k][tx * 4 + j];
      #pragma unroll
      for (int i = 0; i < 4; i++)
        #pragma unroll
        for (int j = 0; j < 4; j++) acc[i][j] += a[i] * bb[j];
    }
    __syncthreads();
  }
  #pragma unroll
  for (int i = 0; i < 4; i++) {
    int m = m0 + ty * 4 + i;
    float bv_ = bias[m];
    #pragma unroll
    for (int j = 0; j < 4; j++) {
      size_t idx = (size_t)(b * 256 + m) * 1024 + l0 + tx * 4 + j;
      out[idx] = acc[i][j] + bv_ + x[idx];
    }
  }
}

extern "C" void kernel_launch(void* const* d_in, const int* in_sizes, int n_in,
                              void* d_out, int out_size, void* d_ws, size_t ws_size,
                              hipStream_t stream) {
  // input-order resolver (dict order proven; kept as cheap insurance)
  int ix = 0, iga = 1, ibe = 2, iwq = 3, ibq = 4, iwk = 5, ibk = 6,
      iwv = 7, ibv = 8, iwp = 9, ibp = 10;
  if (in_sizes[0] != 4194304) {
    if (in_sizes[10] == 4194304 && in_sizes[1] == 256) {
      ibe = 0; ibk = 1; ibp = 2; ibq = 3; ibv = 4; iga = 5;
      iwk = 6; iwp = 7; iwq = 8; iwv = 9; ix = 10;
    } else if (in_sizes[10] == 4194304 && in_sizes[1] == 65536) {
      ibp = 0; iwp = 1; ibv = 2; iwv = 3; ibk = 4; iwk = 5;
      ibq = 6; iwq = 7; ibe = 8; iga = 9; ix = 10;
    } else {
      for (int i = 0; i < 11; i++) if (in_sizes[i] == 4194304) ix = i;
    }
  }
  const float* x     = (const float*)d_in[ix];
  const float* gamma = (const float*)d_in[iga];
  const float* beta  = (const float*)d_in[ibe];
  const float* wq    = (const float*)d_in[iwq];
  const float* bq    = (const float*)d_in[ibq];
  const float* wk    = (const float*)d_in[iwk];
  const float* bk    = (const float*)d_in[ibk];
  const float* wv    = (const float*)d_in[iwv];
  const float* bv    = (const float*)d_in[ibv];
  const float* wproj = (const float*)d_in[iwp];
  const float* bproj = (const float*)d_in[ibp];
  float* out = (float*)d_out;

  const size_t QKV_B = (size_t)768 * 1024;
  const size_t O_B   = (size_t)256 * 1024;
  char* wsp = (char*)d_ws;
  float2* stats = (float2*)wsp;              // 4 KB
  const size_t DATA0 = 8192;
  size_t full_need = DATA0 + 16 * QKV_B * 2 + 16 * O_B * 2;   // ~33.6 MB

  stats_kernel<<<512, 256, 0, stream>>>(x, stats);

  if (ws_size >= full_need) {
    bf16* qkv = (bf16*)(wsp + DATA0);
    bf16* o   = (bf16*)(wsp + DATA0 + 16 * QKV_B * 2);
    gemm_qkv <<<dim3(16, 12, 16), 256, 0, stream>>>(x, gamma, beta, stats,
        wq, bq, wk, bk, wv, bv, qkv, 0, QKV_B);
    attn_kernel<<<dim3(64, 4, 16), 256, 0, stream>>>(qkv, o, QKV_B, O_B);
    gemm_proj<<<dim3(16, 4, 16), 256, 0, stream>>>(wproj, o, bproj, x, out,
        0, O_B);
  } else {
    bf16* qkv = (bf16*)(wsp + DATA0);
    bf16* o   = (bf16*)(wsp + DATA0 + QKV_B * 2);
    for (int b = 0; b < 16; b++) {
      gemm_qkv <<<dim3(16, 12, 1), 256, 0, stream>>>(x, gamma, beta, stats,
          wq, bq, wk, bk, wv, bv, qkv, b, 0);
      attn_kernel<<<dim3(64, 4, 1), 256, 0, stream>>>(qkv, o, 0, 0);
      gemm_proj<<<dim3(16, 4, 1), 256, 0, stream>>>(wproj, o, bproj, x, out,
          b, 0);
    }
  }
}

// Round 14
// 419.233 us; speedup vs baseline: 2.1843x; 1.1187x over previous
//
#include <hip/hip_runtime.h>
#include <hip/hip_bf16.h>
#include <stdint.h>

// Problem constants (B=16, C=256, NH=4, D=64, G=32, L=HW=1024)
// Round 14: kill the K-transpose staging. R13: attn 188us, MfmaUtil 3.7%,
// VALUBusy 49%, 1.05e7 bank-conflict cycles -> time goes to 256 scalar u16
// global loads/thread staging K^T, not MFMA (floor ~7us). Fix: gemm_qkv now
// stores the K section PRE-TRANSPOSED (K^T[head][l][d]); attention computes
// S^T = K^T x Q with both operands natural:
//   A-frag = K^T chunk rows (coalesced dwordx4 stage -> b128 LDS reads)
//   B-frag = Q fragment, loaded once per wave (16 scalar loads total)
// D[row=m][col=qi] scatters into row-major P in LDS = PV A-frag layout.
// Ks rows padded to 72 elems, Ss to 1040 (16B-aligned b128 frags, ~2-way);
// softmax passes packed uint32 (2xbf16). PV unchanged (16B global V loads).
// stats/gemm_proj untouched; qkv epilogue is the only producer change.

typedef __hip_bfloat16 bf16;
typedef __attribute__((ext_vector_type(8))) short short8;
typedef __attribute__((ext_vector_type(4))) float float4v;

__global__ __launch_bounds__(256) void stats_kernel(const float* __restrict__ x,
    float2* __restrict__ stats) {
  int b = blockIdx.x >> 5, g = blockIdx.x & 31;
  const float* xp = x + (size_t)(b * 256 + g * 8) * 1024;
  float s = 0.f, ss = 0.f;
  for (int i = threadIdx.x; i < 8192; i += 256) {
    float v = xp[i]; s += v; ss += v * v;
  }
  #pragma unroll
  for (int o = 32; o; o >>= 1) { s += __shfl_down(s, o); ss += __shfl_down(ss, o); }
  __shared__ float red[2][4];
  int wid = threadIdx.x >> 6;
  if ((threadIdx.x & 63) == 0) { red[0][wid] = s; red[1][wid] = ss; }
  __syncthreads();
  if (threadIdx.x == 0) {
    s  = red[0][0] + red[0][1] + red[0][2] + red[0][3];
    ss = red[1][0] + red[1][1] + red[1][2] + red[1][3];
    float mean = s * (1.f / 8192.f);
    float var  = ss * (1.f / 8192.f) - mean * mean;
    stats[blockIdx.x] = make_float2(mean, rsqrtf(var + 1e-5f));
  }
}

// qkv[b]: Q rows 0-255 as [d_global][l]; K section stored TRANSPOSED as
// K^T[head][l][d] at offset 256*1024 + head*65536; V rows 512-767 as [d][l].
__global__ __launch_bounds__(256) void gemm_qkv(
    const float* __restrict__ x, const float* __restrict__ gamma,
    const float* __restrict__ beta, const float2* __restrict__ stats,
    const float* __restrict__ wq, const float* __restrict__ bq,
    const float* __restrict__ wk, const float* __restrict__ bk,
    const float* __restrict__ wv, const float* __restrict__ bv,
    bf16* __restrict__ qkv, int b_off, size_t qkv_bstride) {
  __shared__ float As[16][65];
  __shared__ float Bs[16][65];
  int zb = blockIdx.z;
  int b  = zb + b_off;
  int m0 = blockIdx.y * 64, l0 = blockIdx.x * 64;
  int sec = m0 >> 8;
  const float* W  = (sec == 0) ? wq : (sec == 1) ? wk : wv;
  const float* bi = (sec == 0) ? bq : (sec == 1) ? bk : bv;
  int rr0 = m0 & 255;
  const float*  xb = x + (size_t)b * 256 * 1024;
  const float2* st = stats + b * 32;
  int tid = threadIdx.x;
  int tx = tid & 15, ty = tid >> 4;
  float acc[4][4] = {};
  for (int k0 = 0; k0 < 256; k0 += 16) {
    for (int i = tid; i < 1024; i += 256) {
      int k = i >> 6, mm = i & 63;
      As[k][mm] = W[(size_t)(rr0 + mm) * 256 + k0 + k];
      int c = k0 + k;
      float2 s2 = st[c >> 3];
      Bs[k][mm] = (xb[(size_t)c * 1024 + l0 + mm] - s2.x) * s2.y * gamma[c] + beta[c];
    }
    __syncthreads();
    #pragma unroll
    for (int k = 0; k < 16; k++) {
      float a[4], bb[4];
      #pragma unroll
      for (int i = 0; i < 4; i++) a[i] = As[k][ty * 4 + i];
      #pragma unroll
      for (int j = 0; j < 4; j++) bb[j] = Bs[k][tx * 4 + j];
      #pragma unroll
      for (int i = 0; i < 4; i++)
        #pragma unroll
        for (int j = 0; j < 4; j++) acc[i][j] += a[i] * bb[j];
    }
    __syncthreads();
  }
  bf16* Cp = qkv + (size_t)zb * qkv_bstride;
  if (sec == 1) {
    // K^T store: head = rr0>>6, d = ty*4+i (0..63), l = l0+tx*4+j
    bf16* Kp = Cp + 256 * 1024 + (rr0 >> 6) * 65536;
    #pragma unroll
    for (int i = 0; i < 4; i++) {
      float bv_ = bi[rr0 + ty * 4 + i];
      #pragma unroll
      for (int j = 0; j < 4; j++)
        Kp[(size_t)(l0 + tx * 4 + j) * 64 + ty * 4 + i] =
            __float2bfloat16(acc[i][j] + bv_);
    }
  } else {
    #pragma unroll
    for (int i = 0; i < 4; i++) {
      float bv_ = bi[rr0 + ty * 4 + i];
      #pragma unroll
      for (int j = 0; j < 4; j++)
        Cp[(size_t)(m0 + ty * 4 + i) * 1024 + l0 + tx * 4 + j] =
            __float2bfloat16(acc[i][j] + bv_);
    }
  }
}

// MFMA attention: one block per (b, head, 16-row q tile).
__global__ __launch_bounds__(256) void attn_kernel(
    const bf16* __restrict__ qkv, bf16* __restrict__ o,
    size_t qkv_bstride, size_t o_bstride) {
  __shared__ bf16 Ks[128][72];     // K^T chunk [m_local][d]; 144B rows (16B-mult)
  __shared__ bf16 Ss[16][1040];    // S then P; 2080B rows (16B-mult)
  __shared__ float invs[16];

  int zb = blockIdx.z, n = blockIdx.y;
  int q0 = blockIdx.x * 16;
  const bf16* base = qkv + (size_t)zb * qkv_bstride;
  const bf16* Qp  = base + (size_t)(n * 64) * 1024;
  const bf16* KTp = base + (size_t)256 * 1024 + (size_t)n * 65536;  // [l][64]
  const bf16* Vp  = base + (size_t)512 * 1024 + (size_t)(n * 64) * 1024;
  int tid = threadIdx.x;
  int lane = tid & 63, wave = tid >> 6;
  int l16 = lane & 15, quad = lane >> 4;

  // B-frag (Q) once per wave: qf[h][j] = Q[h*32+quad*8+j][q0+l16]
  short8 qf[2];
  #pragma unroll
  for (int h = 0; h < 2; h++)
    #pragma unroll
    for (int j = 0; j < 8; j++)
      ((short*)&qf[h])[j] =
          *(const short*)&Qp[(size_t)(h * 32 + quad * 8 + j) * 1024 + q0 + l16];

  // ---- S^T phase: 8 chunks of 128 keys ----
  for (int mc = 0; mc < 8; mc++) {
    __syncthreads();
    const bf16* src = KTp + (size_t)mc * 8192;    // contiguous 16 KB chunk
    #pragma unroll
    for (int it = 0; it < 4; it++) {
      int g = (it * 256 + tid) * 8;
      *(short8*)&Ks[g >> 6][g & 63] = *(const short8*)&src[g];
    }
    __syncthreads();
    #pragma unroll
    for (int s = 0; s < 2; s++) {
      int st = wave * 2 + s;
      float4v acc = {0.f, 0.f, 0.f, 0.f};
      #pragma unroll
      for (int h = 0; h < 2; h++) {
        short8 af = *(const short8*)&Ks[st * 16 + l16][h * 32 + quad * 8];
        acc = __builtin_amdgcn_mfma_f32_16x16x32_bf16(af, qf[h], acc, 0, 0, 0);
      }
      #pragma unroll
      for (int r = 0; r < 4; r++)    // D[row=m_sub][col=qi] -> Ss[qi][m]
        Ss[l16][mc * 128 + st * 16 + quad * 4 + r] =
            __float2bfloat16(acc[r] * 0.125f);
    }
  }
  __syncthreads();

  // ---- softmax: 16 lanes per row, packed 2xbf16 passes ----
  {
    int r = tid >> 4, j = tid & 15;
    uint32_t* row = (uint32_t*)&Ss[r][0];
    float mx = -1e30f;
    for (int t = j; t < 512; t += 16) {
      uint32_t w = row[t];
      bf16 lo = *(bf16*)&w, hi = *((bf16*)&w + 1);
      mx = fmaxf(mx, fmaxf(__bfloat162float(lo), __bfloat162float(hi)));
    }
    #pragma unroll
    for (int off = 8; off; off >>= 1) mx = fmaxf(mx, __shfl_xor(mx, off, 16));
    float sum = 0.f;
    for (int t = j; t < 512; t += 16) {
      uint32_t w = row[t];
      bf16 lo = *(bf16*)&w, hi = *((bf16*)&w + 1);
      float a = __expf(__bfloat162float(lo) - mx);
      float b = __expf(__bfloat162float(hi) - mx);
      sum += a + b;
      bf16 pa = __float2bfloat16(a), pb = __float2bfloat16(b);
      uint32_t pw = (uint32_t)*(uint16_t*)&pa | ((uint32_t)*(uint16_t*)&pb << 16);
      row[t] = pw;
    }
    #pragma unroll
    for (int off = 8; off; off >>= 1) sum += __shfl_xor(sum, off, 16);
    if (j == 0) invs[r] = 1.f / sum;
  }
  __syncthreads();

  // ---- PV: wave w -> d-tile [w*16, w*16+16); K-dim 1024 = 32 x 32 ----
  {
    int d0 = wave * 16;
    float4v acc = {0.f, 0.f, 0.f, 0.f};
    const bf16* vrow = Vp + (size_t)(d0 + l16) * 1024 + quad * 8;
    for (int kt = 0; kt < 32; kt++) {
      short8 af = *(const short8*)&Ss[l16][kt * 32 + quad * 8];
      short8 bf = *(const short8*)(vrow + kt * 32);   // 16B global load
      acc = __builtin_amdgcn_mfma_f32_16x16x32_bf16(af, bf, acc, 0, 0, 0);
    }
    bf16* op = o + (size_t)zb * o_bstride + (size_t)(n * 64 + d0 + l16) * 1024 + q0;
    #pragma unroll
    for (int r = 0; r < 4; r++) {
      int qi = quad * 4 + r;                 // D[row=qi][col=d]
      op[qi] = __float2bfloat16(acc[r] * invs[qi]);
    }
  }
}

// out[b][c][l] = sum_e wproj[c][e]*o[e][l] + bproj[c] + x[b][c][l] -> FLOAT32
__global__ __launch_bounds__(256) void gemm_proj(const float* __restrict__ A,
    const bf16* __restrict__ o, const float* __restrict__ bias,
    const float* __restrict__ x, float* __restrict__ out,
    int b_off, size_t o_bstride) {
  __shared__ float As[16][65];
  __shared__ float Bs[16][65];
  int zb = blockIdx.z;
  int b  = zb + b_off;
  int m0 = blockIdx.y * 64, l0 = blockIdx.x * 64;
  const bf16* op = o + (size_t)zb * o_bstride;
  int tid = threadIdx.x;
  int tx = tid & 15, ty = tid >> 4;
  float acc[4][4] = {};
  for (int k0 = 0; k0 < 256; k0 += 16) {
    for (int i = tid; i < 1024; i += 256) {
      int k = i >> 6, mm = i & 63;
      As[k][mm] = A[(size_t)(m0 + mm) * 256 + k0 + k];
      Bs[k][mm] = __bfloat162float(op[(size_t)(k0 + k) * 1024 + l0 + mm]);
    }
    __syncthreads();
    #pragma unroll
    for (int k = 0; k < 16; k++) {
      float a[4], bb[4];
      #pragma unroll
      for (int i = 0; i < 4; i++) a[i] = As[k][ty * 4 + i];
      #pragma unroll
      for (int j = 0; j < 4; j++) bb[j] = Bs[k][tx * 4 + j];
      #pragma unroll
      for (int i = 0; i < 4; i++)
        #pragma unroll
        for (int j = 0; j < 4; j++) acc[i][j] += a[i] * bb[j];
    }
    __syncthreads();
  }
  #pragma unroll
  for (int i = 0; i < 4; i++) {
    int m = m0 + ty * 4 + i;
    float bv_ = bias[m];
    #pragma unroll
    for (int j = 0; j < 4; j++) {
      size_t idx = (size_t)(b * 256 + m) * 1024 + l0 + tx * 4 + j;
      out[idx] = acc[i][j] + bv_ + x[idx];
    }
  }
}

extern "C" void kernel_launch(void* const* d_in, const int* in_sizes, int n_in,
                              void* d_out, int out_size, void* d_ws, size_t ws_size,
                              hipStream_t stream) {
  int ix = 0, iga = 1, ibe = 2, iwq = 3, ibq = 4, iwk = 5, ibk = 6,
      iwv = 7, ibv = 8, iwp = 9, ibp = 10;
  if (in_sizes[0] != 4194304) {
    if (in_sizes[10] == 4194304 && in_sizes[1] == 256) {
      ibe = 0; ibk = 1; ibp = 2; ibq = 3; ibv = 4; iga = 5;
      iwk = 6; iwp = 7; iwq = 8; iwv = 9; ix = 10;
    } else if (in_sizes[10] == 4194304 && in_sizes[1] == 65536) {
      ibp = 0; iwp = 1; ibv = 2; iwv = 3; ibk = 4; iwk = 5;
      ibq = 6; iwq = 7; ibe = 8; iga = 9; ix = 10;
    } else {
      for (int i = 0; i < 11; i++) if (in_sizes[i] == 4194304) ix = i;
    }
  }
  const float* x     = (const float*)d_in[ix];
  const float* gamma = (const float*)d_in[iga];
  const float* beta  = (const float*)d_in[ibe];
  const float* wq    = (const float*)d_in[iwq];
  const float* bq    = (const float*)d_in[ibq];
  const float* wk    = (const float*)d_in[iwk];
  const float* bk    = (const float*)d_in[ibk];
  const float* wv    = (const float*)d_in[iwv];
  const float* bv    = (const float*)d_in[ibv];
  const float* wproj = (const float*)d_in[iwp];
  const float* bproj = (const float*)d_in[ibp];
  float* out = (float*)d_out;

  const size_t QKV_B = (size_t)768 * 1024;
  const size_t O_B   = (size_t)256 * 1024;
  char* wsp = (char*)d_ws;
  float2* stats = (float2*)wsp;              // 4 KB
  const size_t DATA0 = 8192;
  size_t full_need = DATA0 + 16 * QKV_B * 2 + 16 * O_B * 2;   // ~33.6 MB

  stats_kernel<<<512, 256, 0, stream>>>(x, stats);

  if (ws_size >= full_need) {
    bf16* qkv = (bf16*)(wsp + DATA0);
    bf16* o   = (bf16*)(wsp + DATA0 + 16 * QKV_B * 2);
    gemm_qkv <<<dim3(16, 12, 16), 256, 0, stream>>>(x, gamma, beta, stats,
        wq, bq, wk, bk, wv, bv, qkv, 0, QKV_B);
    attn_kernel<<<dim3(64, 4, 16), 256, 0, stream>>>(qkv, o, QKV_B, O_B);
    gemm_proj<<<dim3(16, 4, 16), 256, 0, stream>>>(wproj, o, bproj, x, out,
        0, O_B);
  } else {
    bf16* qkv = (bf16*)(wsp + DATA0);
    bf16* o   = (bf16*)(wsp + DATA0 + QKV_B * 2);
    for (int b = 0; b < 16; b++) {
      gemm_qkv <<<dim3(16, 12, 1), 256, 0, stream>>>(x, gamma, beta, stats,
          wq, bq, wk, bk, wv, bv, qkv, b, 0);
      attn_kernel<<<dim3(64, 4, 1), 256, 0, stream>>>(qkv, o, 0, 0);
      gemm_proj<<<dim3(16, 4, 1), 256, 0, stream>>>(wproj, o, bproj, x, out,
          b, 0);
    }
  }
}

// Round 15
// 260.737 us; speedup vs baseline: 3.5121x; 1.6079x over previous
//
#include <hip/hip_runtime.h>
#include <hip/hip_bf16.h>
#include <stdint.h>

// Problem constants (B=16, C=256, NH=4, D=64, G=32, L=HW=1024)
// Round 15: MFMA-ize the two GEMMs. R14: gemm_qkv top dispatch 179us,
// MfmaUtil=0, VALUBusy=39%, 1.9e7 bank-conflict cyc (fp32 SIMD GEMM).
// New structure:
//   stats_kernel   : per (b,group) mean/rsqrt (unchanged)
//   gnt_kernel     : GN + LDS-tile transpose -> hT[b][l][c] bf16 (8 MB)
//   wpack          : wq/wk/wv -> Wb[768][256] bf16; wproj -> Pb bf16
//   gemm_qkv_mfma  : 128x128 tile, 4 waves x 4x4 16x16x32-bf16 frags; A=Wb
//                    rows, B=hT rows (both b128 LDS reads, pad-40 rows);
//                    epilogue keeps R14 contract: Q [d][l], K^T [head][l][d],
//                    V [d][l], + bias
//   attn_kernel    : unchanged core; epilogue now writes oT[l][e] (coalesced,
//                    and proj B-frags become contiguous)
//   gemm_proj_mfma : from Pb x oT; epilogue + bproj + x -> f32 out
// ws: stats 4K | Wb 384K | Pb 128K | hT 8M (reused as oT) | qkv 24M ~= 34.1MB
// guarded; per-batch fallback ~2.6 MB.

typedef __hip_bfloat16 bf16;
typedef __attribute__((ext_vector_type(8))) short short8;
typedef __attribute__((ext_vector_type(4))) float float4v;

__global__ __launch_bounds__(256) void stats_kernel(const float* __restrict__ x,
    float2* __restrict__ stats) {
  int b = blockIdx.x >> 5, g = blockIdx.x & 31;
  const float* xp = x + (size_t)(b * 256 + g * 8) * 1024;
  float s = 0.f, ss = 0.f;
  for (int i = threadIdx.x; i < 8192; i += 256) {
    float v = xp[i]; s += v; ss += v * v;
  }
  #pragma unroll
  for (int o = 32; o; o >>= 1) { s += __shfl_down(s, o); ss += __shfl_down(ss, o); }
  __shared__ float red[2][4];
  int wid = threadIdx.x >> 6;
  if ((threadIdx.x & 63) == 0) { red[0][wid] = s; red[1][wid] = ss; }
  __syncthreads();
  if (threadIdx.x == 0) {
    s  = red[0][0] + red[0][1] + red[0][2] + red[0][3];
    ss = red[1][0] + red[1][1] + red[1][2] + red[1][3];
    float mean = s * (1.f / 8192.f);
    float var  = ss * (1.f / 8192.f) - mean * mean;
    stats[blockIdx.x] = make_float2(mean, rsqrtf(var + 1e-5f));
  }
}

// GN + transpose: hT[zb][l][c] = GN(x)[b][c][l], bf16.
__global__ __launch_bounds__(256) void gnt_kernel(const float* __restrict__ x,
    const float* __restrict__ gamma, const float* __restrict__ beta,
    const float2* __restrict__ stats, bf16* __restrict__ hT, int b_off) {
  __shared__ float T[64][65];
  int zb = blockIdx.z, b = zb + b_off;
  int c0 = blockIdx.y * 64, l0 = blockIdx.x * 64;
  const float* xb = x + (size_t)b * 262144;
  const float2* st = stats + b * 32;
  int tid = threadIdx.x;
  for (int i = tid; i < 4096; i += 256) {
    int cl = i >> 6, ll = i & 63;
    int c = c0 + cl;
    float2 s2 = st[c >> 3];
    T[cl][ll] = (xb[(size_t)c * 1024 + l0 + ll] - s2.x) * s2.y * gamma[c] + beta[c];
  }
  __syncthreads();
  bf16* hb = hT + (size_t)zb * 262144;
  for (int i = tid; i < 4096; i += 256) {
    int ll = i >> 6, cl = i & 63;
    hb[(size_t)(l0 + ll) * 256 + c0 + cl] = __float2bfloat16(T[cl][ll]);
  }
}

__global__ __launch_bounds__(256) void wpack(const float* __restrict__ wq,
    const float* __restrict__ wk, const float* __restrict__ wv,
    const float* __restrict__ wp, bf16* __restrict__ Wb, bf16* __restrict__ Pb) {
  int i = blockIdx.x * 256 + threadIdx.x;        // 262144 total
  if (i < 196608) {
    int r = i >> 8, c = i & 255;
    const float* src = (r < 256) ? wq : (r < 512) ? wk : wv;
    Wb[i] = __float2bfloat16(src[(r & 255) * 256 + c]);
  } else {
    int j = i - 196608;
    Pb[j] = __float2bfloat16(wp[j]);
  }
}

// qkv GEMM on MFMA: C[m][l] = Wb[m][:]·h[:][l] + bias. B^T = hT rows.
__global__ __launch_bounds__(256) void gemm_qkv_mfma(
    const bf16* __restrict__ hT, const bf16* __restrict__ Wb,
    const float* __restrict__ bq, const float* __restrict__ bk,
    const float* __restrict__ bv,
    bf16* __restrict__ qkv, size_t qkv_bstride) {
  __shared__ bf16 As[128][40];
  __shared__ bf16 Bs[128][40];
  int zb = blockIdx.z;
  int m0 = blockIdx.y * 128, l0 = blockIdx.x * 128;
  const bf16* hb = hT + (size_t)zb * 262144;
  int tid = threadIdx.x, lane = tid & 63, wave = tid >> 6;
  int l16 = lane & 15, quad = lane >> 4;
  int mi0 = (wave & 1) * 4, nj0 = (wave >> 1) * 4;
  float4v acc[4][4];
  #pragma unroll
  for (int i = 0; i < 4; i++)
    #pragma unroll
    for (int j = 0; j < 4; j++) acc[i][j] = (float4v){0.f, 0.f, 0.f, 0.f};

  for (int kc = 0; kc < 8; kc++) {
    __syncthreads();
    #pragma unroll
    for (int it = 0; it < 2; it++) {
      int s = it * 256 + tid;            // 0..511
      int mm = s >> 2, kk = (s & 3) * 8;
      *(short8*)&As[mm][kk] = *(const short8*)&Wb[(size_t)(m0 + mm) * 256 + kc * 32 + kk];
      *(short8*)&Bs[mm][kk] = *(const short8*)&hb[(size_t)(l0 + mm) * 256 + kc * 32 + kk];
    }
    __syncthreads();
    short8 af[4], bfr[4];
    #pragma unroll
    for (int i = 0; i < 4; i++) af[i]  = *(const short8*)&As[(mi0 + i) * 16 + l16][quad * 8];
    #pragma unroll
    for (int j = 0; j < 4; j++) bfr[j] = *(const short8*)&Bs[(nj0 + j) * 16 + l16][quad * 8];
    #pragma unroll
    for (int i = 0; i < 4; i++)
      #pragma unroll
      for (int j = 0; j < 4; j++)
        acc[i][j] = __builtin_amdgcn_mfma_f32_16x16x32_bf16(af[i], bfr[j], acc[i][j], 0, 0, 0);
  }

  bf16* Cp = qkv + (size_t)zb * qkv_bstride;
  int sec = m0 >> 8;
  const float* bptr = (sec == 0) ? bq : (sec == 1) ? bk : bv;
  #pragma unroll
  for (int i = 0; i < 4; i++) {
    #pragma unroll
    for (int r = 0; r < 4; r++) {
      int m = m0 + (mi0 + i) * 16 + quad * 4 + r;
      float bias = bptr[m & 255];
      if (sec == 1) {
        int rr = m & 255;
        bf16* Kp = Cp + 256 * 1024 + (rr >> 6) * 65536;
        #pragma unroll
        for (int j = 0; j < 4; j++) {
          int l = l0 + (nj0 + j) * 16 + l16;
          Kp[(size_t)l * 64 + (rr & 63)] = __float2bfloat16(acc[i][j][r] + bias);
        }
      } else {
        #pragma unroll
        for (int j = 0; j < 4; j++) {
          int l = l0 + (nj0 + j) * 16 + l16;
          Cp[(size_t)m * 1024 + l] = __float2bfloat16(acc[i][j][r] + bias);
        }
      }
    }
  }
}

// MFMA attention (R14 core); epilogue writes oT[l][e=256].
__global__ __launch_bounds__(256) void attn_kernel(
    const bf16* __restrict__ qkv, bf16* __restrict__ oT,
    size_t qkv_bstride, size_t o_bstride) {
  __shared__ bf16 Ks[128][72];
  __shared__ bf16 Ss[16][1040];
  __shared__ float invs[16];

  int zb = blockIdx.z, n = blockIdx.y;
  int q0 = blockIdx.x * 16;
  const bf16* base = qkv + (size_t)zb * qkv_bstride;
  const bf16* Qp  = base + (size_t)(n * 64) * 1024;
  const bf16* KTp = base + (size_t)256 * 1024 + (size_t)n * 65536;
  const bf16* Vp  = base + (size_t)512 * 1024 + (size_t)(n * 64) * 1024;
  int tid = threadIdx.x;
  int lane = tid & 63, wave = tid >> 6;
  int l16 = lane & 15, quad = lane >> 4;

  short8 qf[2];
  #pragma unroll
  for (int h = 0; h < 2; h++)
    #pragma unroll
    for (int j = 0; j < 8; j++)
      ((short*)&qf[h])[j] =
          *(const short*)&Qp[(size_t)(h * 32 + quad * 8 + j) * 1024 + q0 + l16];

  for (int mc = 0; mc < 8; mc++) {
    __syncthreads();
    const bf16* src = KTp + (size_t)mc * 8192;
    #pragma unroll
    for (int it = 0; it < 4; it++) {
      int g = (it * 256 + tid) * 8;
      *(short8*)&Ks[g >> 6][g & 63] = *(const short8*)&src[g];
    }
    __syncthreads();
    #pragma unroll
    for (int s = 0; s < 2; s++) {
      int st = wave * 2 + s;
      float4v acc = {0.f, 0.f, 0.f, 0.f};
      #pragma unroll
      for (int h = 0; h < 2; h++) {
        short8 af = *(const short8*)&Ks[st * 16 + l16][h * 32 + quad * 8];
        acc = __builtin_amdgcn_mfma_f32_16x16x32_bf16(af, qf[h], acc, 0, 0, 0);
      }
      #pragma unroll
      for (int r = 0; r < 4; r++)
        Ss[l16][mc * 128 + st * 16 + quad * 4 + r] =
            __float2bfloat16(acc[r] * 0.125f);
    }
  }
  __syncthreads();

  {
    int r = tid >> 4, j = tid & 15;
    uint32_t* row = (uint32_t*)&Ss[r][0];
    float mx = -1e30f;
    for (int t = j; t < 512; t += 16) {
      uint32_t w = row[t];
      bf16 lo = *(bf16*)&w, hi = *((bf16*)&w + 1);
      mx = fmaxf(mx, fmaxf(__bfloat162float(lo), __bfloat162float(hi)));
    }
    #pragma unroll
    for (int off = 8; off; off >>= 1) mx = fmaxf(mx, __shfl_xor(mx, off, 16));
    float sum = 0.f;
    for (int t = j; t < 512; t += 16) {
      uint32_t w = row[t];
      bf16 lo = *(bf16*)&w, hi = *((bf16*)&w + 1);
      float a = __expf(__bfloat162float(lo) - mx);
      float b = __expf(__bfloat162float(hi) - mx);
      sum += a + b;
      bf16 pa = __float2bfloat16(a), pb = __float2bfloat16(b);
      uint32_t pw = (uint32_t)*(uint16_t*)&pa | ((uint32_t)*(uint16_t*)&pb << 16);
      row[t] = pw;
    }
    #pragma unroll
    for (int off = 8; off; off >>= 1) sum += __shfl_xor(sum, off, 16);
    if (j == 0) invs[r] = 1.f / sum;
  }
  __syncthreads();

  {
    int d0 = wave * 16;
    float4v acc = {0.f, 0.f, 0.f, 0.f};
    const bf16* vrow = Vp + (size_t)(d0 + l16) * 1024 + quad * 8;
    for (int kt = 0; kt < 32; kt++) {
      short8 af = *(const short8*)&Ss[l16][kt * 32 + quad * 8];
      short8 bfr = *(const short8*)(vrow + kt * 32);
      acc = __builtin_amdgcn_mfma_f32_16x16x32_bf16(af, bfr, acc, 0, 0, 0);
    }
    bf16* op = oT + (size_t)zb * o_bstride;
    #pragma unroll
    for (int r = 0; r < 4; r++) {
      int qi = quad * 4 + r;
      op[(size_t)(q0 + qi) * 256 + n * 64 + d0 + l16] =
          __float2bfloat16(acc[r] * invs[qi]);
    }
  }
}

// proj GEMM on MFMA: out[b][m][l] = Pb[m][:]·o[:][l] + bproj[m] + x, f32 out.
__global__ __launch_bounds__(256) void gemm_proj_mfma(
    const bf16* __restrict__ Pb, const bf16* __restrict__ oT,
    const float* __restrict__ bproj, const float* __restrict__ x,
    float* __restrict__ out, int b_off, size_t o_bstride) {
  __shared__ bf16 As[128][40];
  __shared__ bf16 Bs[128][40];
  int zb = blockIdx.z, b = zb + b_off;
  int m0 = blockIdx.y * 128, l0 = blockIdx.x * 128;
  const bf16* ob = oT + (size_t)zb * o_bstride;
  int tid = threadIdx.x, lane = tid & 63, wave = tid >> 6;
  int l16 = lane & 15, quad = lane >> 4;
  int mi0 = (wave & 1) * 4, nj0 = (wave >> 1) * 4;
  float4v acc[4][4];
  #pragma unroll
  for (int i = 0; i < 4; i++)
    #pragma unroll
    for (int j = 0; j < 4; j++) acc[i][j] = (float4v){0.f, 0.f, 0.f, 0.f};

  for (int kc = 0; kc < 8; kc++) {
    __syncthreads();
    #pragma unroll
    for (int it = 0; it < 2; it++) {
      int s = it * 256 + tid;
      int mm = s >> 2, kk = (s & 3) * 8;
      *(short8*)&As[mm][kk] = *(const short8*)&Pb[(size_t)(m0 + mm) * 256 + kc * 32 + kk];
      *(short8*)&Bs[mm][kk] = *(const short8*)&ob[(size_t)(l0 + mm) * 256 + kc * 32 + kk];
    }
    __syncthreads();
    short8 af[4], bfr[4];
    #pragma unroll
    for (int i = 0; i < 4; i++) af[i]  = *(const short8*)&As[(mi0 + i) * 16 + l16][quad * 8];
    #pragma unroll
    for (int j = 0; j < 4; j++) bfr[j] = *(const short8*)&Bs[(nj0 + j) * 16 + l16][quad * 8];
    #pragma unroll
    for (int i = 0; i < 4; i++)
      #pragma unroll
      for (int j = 0; j < 4; j++)
        acc[i][j] = __builtin_amdgcn_mfma_f32_16x16x32_bf16(af[i], bfr[j], acc[i][j], 0, 0, 0);
  }

  #pragma unroll
  for (int i = 0; i < 4; i++) {
    #pragma unroll
    for (int r = 0; r < 4; r++) {
      int m = m0 + (mi0 + i) * 16 + quad * 4 + r;
      float bias = bproj[m];
      #pragma unroll
      for (int j = 0; j < 4; j++) {
        int l = l0 + (nj0 + j) * 16 + l16;
        size_t idx = (size_t)(b * 256 + m) * 1024 + l;
        out[idx] = acc[i][j][r] + bias + x[idx];
      }
    }
  }
}

extern "C" void kernel_launch(void* const* d_in, const int* in_sizes, int n_in,
                              void* d_out, int out_size, void* d_ws, size_t ws_size,
                              hipStream_t stream) {
  int ix = 0, iga = 1, ibe = 2, iwq = 3, ibq = 4, iwk = 5, ibk = 6,
      iwv = 7, ibv = 8, iwp = 9, ibp = 10;
  if (in_sizes[0] != 4194304) {
    if (in_sizes[10] == 4194304 && in_sizes[1] == 256) {
      ibe = 0; ibk = 1; ibp = 2; ibq = 3; ibv = 4; iga = 5;
      iwk = 6; iwp = 7; iwq = 8; iwv = 9; ix = 10;
    } else if (in_sizes[10] == 4194304 && in_sizes[1] == 65536) {
      ibp = 0; iwp = 1; ibv = 2; iwv = 3; ibk = 4; iwk = 5;
      ibq = 6; iwq = 7; ibe = 8; iga = 9; ix = 10;
    } else {
      for (int i = 0; i < 11; i++) if (in_sizes[i] == 4194304) ix = i;
    }
  }
  const float* x     = (const float*)d_in[ix];
  const float* gamma = (const float*)d_in[iga];
  const float* beta  = (const float*)d_in[ibe];
  const float* wq    = (const float*)d_in[iwq];
  const float* bq    = (const float*)d_in[ibq];
  const float* wk    = (const float*)d_in[iwk];
  const float* bk    = (const float*)d_in[ibk];
  const float* wv    = (const float*)d_in[iwv];
  const float* bv    = (const float*)d_in[ibv];
  const float* wproj = (const float*)d_in[iwp];
  const float* bproj = (const float*)d_in[ibp];
  float* out = (float*)d_out;

  const size_t QKV_B = (size_t)768 * 1024;   // elems/batch
  const size_t O_B   = (size_t)256 * 1024;
  char* wsp = (char*)d_ws;
  float2* stats = (float2*)wsp;                        // 4 KB
  bf16* Wb = (bf16*)(wsp + 8192);                      // 384 KB
  bf16* Pb = (bf16*)(wsp + 8192 + 393216);             // 128 KB
  const size_t HT0 = 8192 + 393216 + 131072;           // = 532480
  size_t full_need = HT0 + (size_t)16 * O_B * 2 + (size_t)16 * QKV_B * 2; // ~34.1 MB

  stats_kernel<<<512, 256, 0, stream>>>(x, stats);
  wpack<<<1024, 256, 0, stream>>>(wq, wk, wv, wproj, Wb, Pb);

  if (ws_size >= full_need) {
    bf16* hT  = (bf16*)(wsp + HT0);                    // 8 MB; reused as oT
    bf16* qkv = (bf16*)(wsp + HT0 + 16 * O_B * 2);     // 24 MB
    bf16* oT  = hT;
    gnt_kernel   <<<dim3(16, 4, 16), 256, 0, stream>>>(x, gamma, beta, stats, hT, 0);
    gemm_qkv_mfma<<<dim3(8, 6, 16), 256, 0, stream>>>(hT, Wb, bq, bk, bv, qkv, QKV_B);
    attn_kernel  <<<dim3(64, 4, 16), 256, 0, stream>>>(qkv, oT, QKV_B, O_B);
    gemm_proj_mfma<<<dim3(8, 2, 16), 256, 0, stream>>>(Pb, oT, bproj, x, out, 0, O_B);
  } else {
    bf16* hT  = (bf16*)(wsp + HT0);                    // 512 KB per batch
    bf16* qkv = (bf16*)(wsp + HT0 + O_B * 2);          // 1.5 MB
    bf16* oT  = hT;
    for (int b = 0; b < 16; b++) {
      gnt_kernel   <<<dim3(16, 4, 1), 256, 0, stream>>>(x, gamma, beta, stats, hT, b);
      gemm_qkv_mfma<<<dim3(8, 6, 1), 256, 0, stream>>>(hT, Wb, bq, bk, bv, qkv, 0);
      attn_kernel  <<<dim3(64, 4, 1), 256, 0, stream>>>(qkv, oT, 0, 0);
      gemm_proj_mfma<<<dim3(8, 2, 1), 256, 0, stream>>>(Pb, oT, bproj, x, out, b, 0);
    }
  }
}

// Round 16
// 230.840 us; speedup vs baseline: 3.9670x; 1.1295x over previous
//
#include <hip/hip_runtime.h>
#include <hip/hip_bf16.h>
#include <stdint.h>

// Problem constants (B=16, C=256, NH=4, D=64, G=32, L=HW=1024)
// Round 16: flash-restructured attention. R15: attn 133us top dispatch,
// MfmaUtil 5.2%, VALUBusy 29%, occupancy 31%, 8.4e6 LDS-conflict cyc ->
// latency-bound two-phase structure (S->LDS->3-pass softmax->PV with
// scattered global V). New attn: per 128-key chunk, stage K^T+V coalesced
// into LDS; each wave owns a 32-key slice, keeps S/P in REGISTERS, maintains
// per-wave online-softmax (m,l) via quad-shuffles; P reaches PV A-frag layout
// via 16 __shfl (no LDS roundtrip); PV B-frags = b128 LDS reads of V. Final
// cross-wave combine through a 16KB aliased LDS region. LDS 52->36.4 KB
// (4 blocks/CU). Other kernels unchanged from R15 (MFMA GEMMs, gnt, wpack).

typedef __hip_bfloat16 bf16;
typedef __attribute__((ext_vector_type(8))) short short8;
typedef __attribute__((ext_vector_type(4))) float float4v;

__global__ __launch_bounds__(256) void stats_kernel(const float* __restrict__ x,
    float2* __restrict__ stats) {
  int b = blockIdx.x >> 5, g = blockIdx.x & 31;
  const float* xp = x + (size_t)(b * 256 + g * 8) * 1024;
  float s = 0.f, ss = 0.f;
  for (int i = threadIdx.x; i < 8192; i += 256) {
    float v = xp[i]; s += v; ss += v * v;
  }
  #pragma unroll
  for (int o = 32; o; o >>= 1) { s += __shfl_down(s, o); ss += __shfl_down(ss, o); }
  __shared__ float red[2][4];
  int wid = threadIdx.x >> 6;
  if ((threadIdx.x & 63) == 0) { red[0][wid] = s; red[1][wid] = ss; }
  __syncthreads();
  if (threadIdx.x == 0) {
    s  = red[0][0] + red[0][1] + red[0][2] + red[0][3];
    ss = red[1][0] + red[1][1] + red[1][2] + red[1][3];
    float mean = s * (1.f / 8192.f);
    float var  = ss * (1.f / 8192.f) - mean * mean;
    stats[blockIdx.x] = make_float2(mean, rsqrtf(var + 1e-5f));
  }
}

// GN + transpose: hT[zb][l][c] = GN(x)[b][c][l], bf16.
__global__ __launch_bounds__(256) void gnt_kernel(const float* __restrict__ x,
    const float* __restrict__ gamma, const float* __restrict__ beta,
    const float2* __restrict__ stats, bf16* __restrict__ hT, int b_off) {
  __shared__ float T[64][65];
  int zb = blockIdx.z, b = zb + b_off;
  int c0 = blockIdx.y * 64, l0 = blockIdx.x * 64;
  const float* xb = x + (size_t)b * 262144;
  const float2* st = stats + b * 32;
  int tid = threadIdx.x;
  for (int i = tid; i < 4096; i += 256) {
    int cl = i >> 6, ll = i & 63;
    int c = c0 + cl;
    float2 s2 = st[c >> 3];
    T[cl][ll] = (xb[(size_t)c * 1024 + l0 + ll] - s2.x) * s2.y * gamma[c] + beta[c];
  }
  __syncthreads();
  bf16* hb = hT + (size_t)zb * 262144;
  for (int i = tid; i < 4096; i += 256) {
    int ll = i >> 6, cl = i & 63;
    hb[(size_t)(l0 + ll) * 256 + c0 + cl] = __float2bfloat16(T[cl][ll]);
  }
}

__global__ __launch_bounds__(256) void wpack(const float* __restrict__ wq,
    const float* __restrict__ wk, const float* __restrict__ wv,
    const float* __restrict__ wp, bf16* __restrict__ Wb, bf16* __restrict__ Pb) {
  int i = blockIdx.x * 256 + threadIdx.x;        // 262144 total
  if (i < 196608) {
    int r = i >> 8, c = i & 255;
    const float* src = (r < 256) ? wq : (r < 512) ? wk : wv;
    Wb[i] = __float2bfloat16(src[(r & 255) * 256 + c]);
  } else {
    int j = i - 196608;
    Pb[j] = __float2bfloat16(wp[j]);
  }
}

// qkv GEMM on MFMA: C[m][l] = Wb[m][:]·h[:][l] + bias. B^T = hT rows.
__global__ __launch_bounds__(256) void gemm_qkv_mfma(
    const bf16* __restrict__ hT, const bf16* __restrict__ Wb,
    const float* __restrict__ bq, const float* __restrict__ bk,
    const float* __restrict__ bv,
    bf16* __restrict__ qkv, size_t qkv_bstride) {
  __shared__ bf16 As[128][40];
  __shared__ bf16 Bs[128][40];
  int zb = blockIdx.z;
  int m0 = blockIdx.y * 128, l0 = blockIdx.x * 128;
  const bf16* hb = hT + (size_t)zb * 262144;
  int tid = threadIdx.x, lane = tid & 63, wave = tid >> 6;
  int l16 = lane & 15, quad = lane >> 4;
  int mi0 = (wave & 1) * 4, nj0 = (wave >> 1) * 4;
  float4v acc[4][4];
  #pragma unroll
  for (int i = 0; i < 4; i++)
    #pragma unroll
    for (int j = 0; j < 4; j++) acc[i][j] = (float4v){0.f, 0.f, 0.f, 0.f};

  for (int kc = 0; kc < 8; kc++) {
    __syncthreads();
    #pragma unroll
    for (int it = 0; it < 2; it++) {
      int s = it * 256 + tid;
      int mm = s >> 2, kk = (s & 3) * 8;
      *(short8*)&As[mm][kk] = *(const short8*)&Wb[(size_t)(m0 + mm) * 256 + kc * 32 + kk];
      *(short8*)&Bs[mm][kk] = *(const short8*)&hb[(size_t)(l0 + mm) * 256 + kc * 32 + kk];
    }
    __syncthreads();
    short8 af[4], bfr[4];
    #pragma unroll
    for (int i = 0; i < 4; i++) af[i]  = *(const short8*)&As[(mi0 + i) * 16 + l16][quad * 8];
    #pragma unroll
    for (int j = 0; j < 4; j++) bfr[j] = *(const short8*)&Bs[(nj0 + j) * 16 + l16][quad * 8];
    #pragma unroll
    for (int i = 0; i < 4; i++)
      #pragma unroll
      for (int j = 0; j < 4; j++)
        acc[i][j] = __builtin_amdgcn_mfma_f32_16x16x32_bf16(af[i], bfr[j], acc[i][j], 0, 0, 0);
  }

  bf16* Cp = qkv + (size_t)zb * qkv_bstride;
  int sec = m0 >> 8;
  const float* bptr = (sec == 0) ? bq : (sec == 1) ? bk : bv;
  #pragma unroll
  for (int i = 0; i < 4; i++) {
    #pragma unroll
    for (int r = 0; r < 4; r++) {
      int m = m0 + (mi0 + i) * 16 + quad * 4 + r;
      float bias = bptr[m & 255];
      if (sec == 1) {
        int rr = m & 255;
        bf16* Kp = Cp + 256 * 1024 + (rr >> 6) * 65536;
        #pragma unroll
        for (int j = 0; j < 4; j++) {
          int l = l0 + (nj0 + j) * 16 + l16;
          Kp[(size_t)l * 64 + (rr & 63)] = __float2bfloat16(acc[i][j][r] + bias);
        }
      } else {
        #pragma unroll
        for (int j = 0; j < 4; j++) {
          int l = l0 + (nj0 + j) * 16 + l16;
          Cp[(size_t)m * 1024 + l] = __float2bfloat16(acc[i][j][r] + bias);
        }
      }
    }
  }
}

// Flash MFMA attention: one block per (b, head, 16 q-rows); per-wave online
// softmax over its 32-key slice of each 128-key chunk.
__global__ __launch_bounds__(256) void attn_kernel(
    const bf16* __restrict__ qkv, bf16* __restrict__ oT,
    size_t qkv_bstride, size_t o_bstride) {
  __shared__ __align__(16) char lds_raw[36864];
  bf16 (*Ks)[72]  = (bf16(*)[72])lds_raw;                // [128][72]  18432 B
  bf16 (*Vs)[136] = (bf16(*)[136])(lds_raw + 18432);     // [64][136]  17408 B
  float* mS = (float*)(lds_raw + 35840);                 // [4][16]
  float* lS = (float*)(lds_raw + 36096);                 // [4][16]
  float* Ow = (float*)lds_raw;                           // combine alias (<=16.7 KB)

  int zb = blockIdx.z, n = blockIdx.y;
  int q0 = blockIdx.x * 16;
  const bf16* base = qkv + (size_t)zb * qkv_bstride;
  const bf16* Qp  = base + (size_t)(n * 64) * 1024;
  const bf16* KTp = base + (size_t)256 * 1024 + (size_t)n * 65536;  // [l][64]
  const bf16* Vp  = base + (size_t)512 * 1024 + (size_t)(n * 64) * 1024;
  int tid = threadIdx.x;
  int lane = tid & 63, wave = tid >> 6;
  int l16 = lane & 15, quad = lane >> 4;

  // B-frag (Q) once per wave: qf[h][j] = Q[h*32+quad*8+j][q0+l16]
  short8 qf[2];
  #pragma unroll
  for (int h = 0; h < 2; h++)
    #pragma unroll
    for (int j = 0; j < 8; j++)
      ((short*)&qf[h])[j] =
          *(const short*)&Qp[(size_t)(h * 32 + quad * 8 + j) * 1024 + q0 + l16];

  float m_run = -1e30f, l_run = 0.f;     // for qi = l16 (replicated over quads)
  float4v oacc[4];                        // d-tile dt: rows q=quad*4+r, col d=dt*16+l16
  #pragma unroll
  for (int dt = 0; dt < 4; dt++) oacc[dt] = (float4v){0.f, 0.f, 0.f, 0.f};

  for (int mc = 0; mc < 8; mc++) {
    __syncthreads();                      // protect Ks/Vs reuse
    const bf16* ksrc = KTp + (size_t)mc * 8192;   // contiguous 16 KB
    #pragma unroll
    for (int it = 0; it < 4; it++) {
      int g = (it * 256 + tid) * 8;
      *(short8*)&Ks[g >> 6][g & 63] = *(const short8*)&ksrc[g];
    }
    #pragma unroll
    for (int it = 0; it < 4; it++) {      // Vs[d][m] = V[d][mc*128+m]
      int s = it * 256 + tid;
      int d = s >> 4, cg = (s & 15) * 8;
      *(short8*)&Vs[d][cg] = *(const short8*)&Vp[(size_t)d * 1024 + mc * 128 + cg];
    }
    __syncthreads();

    // S^T MFMAs over this wave's 32 keys: m = mc*128 + wave*32 + s*16 + quad*4 + r
    float sc[2][4];
    #pragma unroll
    for (int s = 0; s < 2; s++) {
      int st = wave * 2 + s;
      float4v a = (float4v){0.f, 0.f, 0.f, 0.f};
      #pragma unroll
      for (int h = 0; h < 2; h++) {
        short8 af = *(const short8*)&Ks[st * 16 + l16][h * 32 + quad * 8];
        a = __builtin_amdgcn_mfma_f32_16x16x32_bf16(af, qf[h], a, 0, 0, 0);
      }
      #pragma unroll
      for (int r = 0; r < 4; r++) sc[s][r] = a[r] * 0.125f;
    }

    // online-softmax update (per qi=l16, over the wave's 32 keys)
    float cmax = sc[0][0];
    #pragma unroll
    for (int s = 0; s < 2; s++)
      #pragma unroll
      for (int r = 0; r < 4; r++) cmax = fmaxf(cmax, sc[s][r]);
    cmax = fmaxf(cmax, __shfl_xor(cmax, 16, 64));
    cmax = fmaxf(cmax, __shfl_xor(cmax, 32, 64));
    float mnew  = fmaxf(m_run, cmax);
    float alpha = __expf(m_run - mnew);
    float pf[2][4];
    float psum = 0.f;
    #pragma unroll
    for (int s = 0; s < 2; s++)
      #pragma unroll
      for (int r = 0; r < 4; r++) {
        pf[s][r] = __expf(sc[s][r] - mnew);
        psum += pf[s][r];
      }
    psum += __shfl_xor(psum, 16, 64);
    psum += __shfl_xor(psum, 32, 64);
    l_run = l_run * alpha + psum;
    m_run = mnew;

    // P -> PV A-frag layout via shuffles: need P[qi=l16][k=quad*8+j]
    short8 paf;
    #pragma unroll
    for (int j = 0; j < 8; j++) {
      int p   = quad * 8 + j;                       // wave-local key index 0..31
      int src = (((p >> 2) & 3) << 4) + l16;        // source lane
      float v0 = __shfl(pf[0][j & 3], src, 64);
      float v1 = __shfl(pf[1][j & 3], src, 64);
      float v  = (quad < 2) ? v0 : v1;              // s = p>>4 = quad>>1
      bf16 pb = __float2bfloat16(v);
      ((short*)&paf)[j] = *(short*)&pb;
    }
    // alpha per output row q = quad*4+r
    float al[4];
    #pragma unroll
    for (int r = 0; r < 4; r++) al[r] = __shfl(alpha, quad * 4 + r, 64);

    // PV MFMAs: K-dim = wave's 32 keys; B = Vs rows
    #pragma unroll
    for (int dt = 0; dt < 4; dt++) {
      float4v c;
      #pragma unroll
      for (int r = 0; r < 4; r++) c[r] = oacc[dt][r] * al[r];
      short8 bfr = *(const short8*)&Vs[dt * 16 + l16][wave * 32 + quad * 8];
      oacc[dt] = __builtin_amdgcn_mfma_f32_16x16x32_bf16(paf, bfr, c, 0, 0, 0);
    }
  }

  // cross-wave combine
  __syncthreads();
  if (quad == 0) { mS[wave * 16 + l16] = m_run; lS[wave * 16 + l16] = l_run; }
  #pragma unroll
  for (int dt = 0; dt < 4; dt++)
    #pragma unroll
    for (int r = 0; r < 4; r++)
      Ow[wave * 1040 + (quad * 4 + r) * 65 + dt * 16 + l16] = oacc[dt][r];
  __syncthreads();

  bf16* op = oT + (size_t)zb * o_bstride;
  #pragma unroll
  for (int k = 0; k < 4; k++) {
    int idx = k * 256 + tid;
    int q = idx >> 6, d = idx & 63;
    float mstar = mS[q];
    #pragma unroll
    for (int w = 1; w < 4; w++) mstar = fmaxf(mstar, mS[w * 16 + q]);
    float num = 0.f, den = 0.f;
    #pragma unroll
    for (int w = 0; w < 4; w++) {
      float e = __expf(mS[w * 16 + q] - mstar);
      den += lS[w * 16 + q] * e;
      num += Ow[w * 1040 + q * 65 + d] * e;
    }
    op[(size_t)(q0 + q) * 256 + n * 64 + d] = __float2bfloat16(num / den);
  }
}

// proj GEMM on MFMA: out[b][m][l] = Pb[m][:]·o[:][l] + bproj[m] + x, f32 out.
__global__ __launch_bounds__(256) void gemm_proj_mfma(
    const bf16* __restrict__ Pb, const bf16* __restrict__ oT,
    const float* __restrict__ bproj, const float* __restrict__ x,
    float* __restrict__ out, int b_off, size_t o_bstride) {
  __shared__ bf16 As[128][40];
  __shared__ bf16 Bs[128][40];
  int zb = blockIdx.z, b = zb + b_off;
  int m0 = blockIdx.y * 128, l0 = blockIdx.x * 128;
  const bf16* ob = oT + (size_t)zb * o_bstride;
  int tid = threadIdx.x, lane = tid & 63, wave = tid >> 6;
  int l16 = lane & 15, quad = lane >> 4;
  int mi0 = (wave & 1) * 4, nj0 = (wave >> 1) * 4;
  float4v acc[4][4];
  #pragma unroll
  for (int i = 0; i < 4; i++)
    #pragma unroll
    for (int j = 0; j < 4; j++) acc[i][j] = (float4v){0.f, 0.f, 0.f, 0.f};

  for (int kc = 0; kc < 8; kc++) {
    __syncthreads();
    #pragma unroll
    for (int it = 0; it < 2; it++) {
      int s = it * 256 + tid;
      int mm = s >> 2, kk = (s & 3) * 8;
      *(short8*)&As[mm][kk] = *(const short8*)&Pb[(size_t)(m0 + mm) * 256 + kc * 32 + kk];
      *(short8*)&Bs[mm][kk] = *(const short8*)&ob[(size_t)(l0 + mm) * 256 + kc * 32 + kk];
    }
    __syncthreads();
    short8 af[4], bfr[4];
    #pragma unroll
    for (int i = 0; i < 4; i++) af[i]  = *(const short8*)&As[(mi0 + i) * 16 + l16][quad * 8];
    #pragma unroll
    for (int j = 0; j < 4; j++) bfr[j] = *(const short8*)&Bs[(nj0 + j) * 16 + l16][quad * 8];
    #pragma unroll
    for (int i = 0; i < 4; i++)
      #pragma unroll
      for (int j = 0; j < 4; j++)
        acc[i][j] = __builtin_amdgcn_mfma_f32_16x16x32_bf16(af[i], bfr[j], acc[i][j], 0, 0, 0);
  }

  #pragma unroll
  for (int i = 0; i < 4; i++) {
    #pragma unroll
    for (int r = 0; r < 4; r++) {
      int m = m0 + (mi0 + i) * 16 + quad * 4 + r;
      float bias = bproj[m];
      #pragma unroll
      for (int j = 0; j < 4; j++) {
        int l = l0 + (nj0 + j) * 16 + l16;
        size_t idx = (size_t)(b * 256 + m) * 1024 + l;
        out[idx] = acc[i][j][r] + bias + x[idx];
      }
    }
  }
}

extern "C" void kernel_launch(void* const* d_in, const int* in_sizes, int n_in,
                              void* d_out, int out_size, void* d_ws, size_t ws_size,
                              hipStream_t stream) {
  int ix = 0, iga = 1, ibe = 2, iwq = 3, ibq = 4, iwk = 5, ibk = 6,
      iwv = 7, ibv = 8, iwp = 9, ibp = 10;
  if (in_sizes[0] != 4194304) {
    if (in_sizes[10] == 4194304 && in_sizes[1] == 256) {
      ibe = 0; ibk = 1; ibp = 2; ibq = 3; ibv = 4; iga = 5;
      iwk = 6; iwp = 7; iwq = 8; iwv = 9; ix = 10;
    } else if (in_sizes[10] == 4194304 && in_sizes[1] == 65536) {
      ibp = 0; iwp = 1; ibv = 2; iwv = 3; ibk = 4; iwk = 5;
      ibq = 6; iwq = 7; ibe = 8; iga = 9; ix = 10;
    } else {
      for (int i = 0; i < 11; i++) if (in_sizes[i] == 4194304) ix = i;
    }
  }
  const float* x     = (const float*)d_in[ix];
  const float* gamma = (const float*)d_in[iga];
  const float* beta  = (const float*)d_in[ibe];
  const float* wq    = (const float*)d_in[iwq];
  const float* bq    = (const float*)d_in[ibq];
  const float* wk    = (const float*)d_in[iwk];
  const float* bk    = (const float*)d_in[ibk];
  const float* wv    = (const float*)d_in[iwv];
  const float* bv    = (const float*)d_in[ibv];
  const float* wproj = (const float*)d_in[iwp];
  const float* bproj = (const float*)d_in[ibp];
  float* out = (float*)d_out;

  const size_t QKV_B = (size_t)768 * 1024;
  const size_t O_B   = (size_t)256 * 1024;
  char* wsp = (char*)d_ws;
  float2* stats = (float2*)wsp;                        // 4 KB
  bf16* Wb = (bf16*)(wsp + 8192);                      // 384 KB
  bf16* Pb = (bf16*)(wsp + 8192 + 393216);             // 128 KB
  const size_t HT0 = 8192 + 393216 + 131072;
  size_t full_need = HT0 + (size_t)16 * O_B * 2 + (size_t)16 * QKV_B * 2; // ~34.1 MB

  stats_kernel<<<512, 256, 0, stream>>>(x, stats);
  wpack<<<1024, 256, 0, stream>>>(wq, wk, wv, wproj, Wb, Pb);

  if (ws_size >= full_need) {
    bf16* hT  = (bf16*)(wsp + HT0);                    // 8 MB; reused as oT
    bf16* qkv = (bf16*)(wsp + HT0 + 16 * O_B * 2);     // 24 MB
    bf16* oT  = hT;
    gnt_kernel   <<<dim3(16, 4, 16), 256, 0, stream>>>(x, gamma, beta, stats, hT, 0);
    gemm_qkv_mfma<<<dim3(8, 6, 16), 256, 0, stream>>>(hT, Wb, bq, bk, bv, qkv, QKV_B);
    attn_kernel  <<<dim3(64, 4, 16), 256, 0, stream>>>(qkv, oT, QKV_B, O_B);
    gemm_proj_mfma<<<dim3(8, 2, 16), 256, 0, stream>>>(Pb, oT, bproj, x, out, 0, O_B);
  } else {
    bf16* hT  = (bf16*)(wsp + HT0);
    bf16* qkv = (bf16*)(wsp + HT0 + O_B * 2);
    bf16* oT  = hT;
    for (int b = 0; b < 16; b++) {
      gnt_kernel   <<<dim3(16, 4, 1), 256, 0, stream>>>(x, gamma, beta, stats, hT, b);
      gemm_qkv_mfma<<<dim3(8, 6, 1), 256, 0, stream>>>(hT, Wb, bq, bk, bv, qkv, 0);
      attn_kernel  <<<dim3(64, 4, 1), 256, 0, stream>>>(qkv, oT, 0, 0);
      gemm_proj_mfma<<<dim3(8, 2, 1), 256, 0, stream>>>(Pb, oT, bproj, x, out, b, 0);
    }
  }
}

// Round 17
// 217.391 us; speedup vs baseline: 4.2124x; 1.0619x over previous
//
#include <hip/hip_runtime.h>
#include <hip/hip_bf16.h>
#include <stdint.h>

// Problem constants (B=16, C=256, NH=4, D=64, G=32, L=HW=1024)
// Round 17: q-tile 16 -> 32 in flash attention. R16: attn 100us, MfmaUtil
// 7.2%, staging-dominated (MFMA floor ~2us/CU vs ~13us LDS traffic; K/V
// re-staged 64x per head). Doubling the q-tile halves blocks (4096->2048),
// halves K/V global re-reads and LDS staging per FLOP. Per wave per chunk:
// 8 S-MFMAs + 8 PV-MFMAs (Vs frags reused across the 2 q-subtiles); online
// (m,l) per subtile; 32 shfls/chunk for P A-frags. LDS 36.9 KB unchanged.
// All other kernels unchanged from R16 (green, absmax 0.03125).

typedef __hip_bfloat16 bf16;
typedef __attribute__((ext_vector_type(8))) short short8;
typedef __attribute__((ext_vector_type(4))) float float4v;

__global__ __launch_bounds__(256) void stats_kernel(const float* __restrict__ x,
    float2* __restrict__ stats) {
  int b = blockIdx.x >> 5, g = blockIdx.x & 31;
  const float* xp = x + (size_t)(b * 256 + g * 8) * 1024;
  float s = 0.f, ss = 0.f;
  for (int i = threadIdx.x; i < 8192; i += 256) {
    float v = xp[i]; s += v; ss += v * v;
  }
  #pragma unroll
  for (int o = 32; o; o >>= 1) { s += __shfl_down(s, o); ss += __shfl_down(ss, o); }
  __shared__ float red[2][4];
  int wid = threadIdx.x >> 6;
  if ((threadIdx.x & 63) == 0) { red[0][wid] = s; red[1][wid] = ss; }
  __syncthreads();
  if (threadIdx.x == 0) {
    s  = red[0][0] + red[0][1] + red[0][2] + red[0][3];
    ss = red[1][0] + red[1][1] + red[1][2] + red[1][3];
    float mean = s * (1.f / 8192.f);
    float var  = ss * (1.f / 8192.f) - mean * mean;
    stats[blockIdx.x] = make_float2(mean, rsqrtf(var + 1e-5f));
  }
}

// GN + transpose: hT[zb][l][c] = GN(x)[b][c][l], bf16.
__global__ __launch_bounds__(256) void gnt_kernel(const float* __restrict__ x,
    const float* __restrict__ gamma, const float* __restrict__ beta,
    const float2* __restrict__ stats, bf16* __restrict__ hT, int b_off) {
  __shared__ float T[64][65];
  int zb = blockIdx.z, b = zb + b_off;
  int c0 = blockIdx.y * 64, l0 = blockIdx.x * 64;
  const float* xb = x + (size_t)b * 262144;
  const float2* st = stats + b * 32;
  int tid = threadIdx.x;
  for (int i = tid; i < 4096; i += 256) {
    int cl = i >> 6, ll = i & 63;
    int c = c0 + cl;
    float2 s2 = st[c >> 3];
    T[cl][ll] = (xb[(size_t)c * 1024 + l0 + ll] - s2.x) * s2.y * gamma[c] + beta[c];
  }
  __syncthreads();
  bf16* hb = hT + (size_t)zb * 262144;
  for (int i = tid; i < 4096; i += 256) {
    int ll = i >> 6, cl = i & 63;
    hb[(size_t)(l0 + ll) * 256 + c0 + cl] = __float2bfloat16(T[cl][ll]);
  }
}

__global__ __launch_bounds__(256) void wpack(const float* __restrict__ wq,
    const float* __restrict__ wk, const float* __restrict__ wv,
    const float* __restrict__ wp, bf16* __restrict__ Wb, bf16* __restrict__ Pb) {
  int i = blockIdx.x * 256 + threadIdx.x;        // 262144 total
  if (i < 196608) {
    int r = i >> 8, c = i & 255;
    const float* src = (r < 256) ? wq : (r < 512) ? wk : wv;
    Wb[i] = __float2bfloat16(src[(r & 255) * 256 + c]);
  } else {
    int j = i - 196608;
    Pb[j] = __float2bfloat16(wp[j]);
  }
}

// qkv GEMM on MFMA: C[m][l] = Wb[m][:]·h[:][l] + bias. B^T = hT rows.
__global__ __launch_bounds__(256) void gemm_qkv_mfma(
    const bf16* __restrict__ hT, const bf16* __restrict__ Wb,
    const float* __restrict__ bq, const float* __restrict__ bk,
    const float* __restrict__ bv,
    bf16* __restrict__ qkv, size_t qkv_bstride) {
  __shared__ bf16 As[128][40];
  __shared__ bf16 Bs[128][40];
  int zb = blockIdx.z;
  int m0 = blockIdx.y * 128, l0 = blockIdx.x * 128;
  const bf16* hb = hT + (size_t)zb * 262144;
  int tid = threadIdx.x, lane = tid & 63, wave = tid >> 6;
  int l16 = lane & 15, quad = lane >> 4;
  int mi0 = (wave & 1) * 4, nj0 = (wave >> 1) * 4;
  float4v acc[4][4];
  #pragma unroll
  for (int i = 0; i < 4; i++)
    #pragma unroll
    for (int j = 0; j < 4; j++) acc[i][j] = (float4v){0.f, 0.f, 0.f, 0.f};

  for (int kc = 0; kc < 8; kc++) {
    __syncthreads();
    #pragma unroll
    for (int it = 0; it < 2; it++) {
      int s = it * 256 + tid;
      int mm = s >> 2, kk = (s & 3) * 8;
      *(short8*)&As[mm][kk] = *(const short8*)&Wb[(size_t)(m0 + mm) * 256 + kc * 32 + kk];
      *(short8*)&Bs[mm][kk] = *(const short8*)&hb[(size_t)(l0 + mm) * 256 + kc * 32 + kk];
    }
    __syncthreads();
    short8 af[4], bfr[4];
    #pragma unroll
    for (int i = 0; i < 4; i++) af[i]  = *(const short8*)&As[(mi0 + i) * 16 + l16][quad * 8];
    #pragma unroll
    for (int j = 0; j < 4; j++) bfr[j] = *(const short8*)&Bs[(nj0 + j) * 16 + l16][quad * 8];
    #pragma unroll
    for (int i = 0; i < 4; i++)
      #pragma unroll
      for (int j = 0; j < 4; j++)
        acc[i][j] = __builtin_amdgcn_mfma_f32_16x16x32_bf16(af[i], bfr[j], acc[i][j], 0, 0, 0);
  }

  bf16* Cp = qkv + (size_t)zb * qkv_bstride;
  int sec = m0 >> 8;
  const float* bptr = (sec == 0) ? bq : (sec == 1) ? bk : bv;
  #pragma unroll
  for (int i = 0; i < 4; i++) {
    #pragma unroll
    for (int r = 0; r < 4; r++) {
      int m = m0 + (mi0 + i) * 16 + quad * 4 + r;
      float bias = bptr[m & 255];
      if (sec == 1) {
        int rr = m & 255;
        bf16* Kp = Cp + 256 * 1024 + (rr >> 6) * 65536;
        #pragma unroll
        for (int j = 0; j < 4; j++) {
          int l = l0 + (nj0 + j) * 16 + l16;
          Kp[(size_t)l * 64 + (rr & 63)] = __float2bfloat16(acc[i][j][r] + bias);
        }
      } else {
        #pragma unroll
        for (int j = 0; j < 4; j++) {
          int l = l0 + (nj0 + j) * 16 + l16;
          Cp[(size_t)m * 1024 + l] = __float2bfloat16(acc[i][j][r] + bias);
        }
      }
    }
  }
}

// Flash MFMA attention: one block per (b, head, 32 q-rows); per-wave online
// softmax over its 32-key slice of each 128-key chunk; 2 q-subtiles.
__global__ __launch_bounds__(256) void attn_kernel(
    const bf16* __restrict__ qkv, bf16* __restrict__ oT,
    size_t qkv_bstride, size_t o_bstride) {
  __shared__ __align__(16) char lds_raw[36864];
  bf16 (*Ks)[72]  = (bf16(*)[72])lds_raw;                // [128][72]  18432 B
  bf16 (*Vs)[136] = (bf16(*)[136])(lds_raw + 18432);     // [64][136]  17408 B
  float* Ow = (float*)lds_raw;                           // combine alias: 4x32x65 f32 = 33280 B
  float* mS = (float*)(lds_raw + 33280);                 // [4][32]
  float* lS = (float*)(lds_raw + 33792);                 // [4][32]

  int zb = blockIdx.z, n = blockIdx.y;
  int q0 = blockIdx.x * 32;
  const bf16* base = qkv + (size_t)zb * qkv_bstride;
  const bf16* Qp  = base + (size_t)(n * 64) * 1024;
  const bf16* KTp = base + (size_t)256 * 1024 + (size_t)n * 65536;  // [l][64]
  const bf16* Vp  = base + (size_t)512 * 1024 + (size_t)(n * 64) * 1024;
  int tid = threadIdx.x;
  int lane = tid & 63, wave = tid >> 6;
  int l16 = lane & 15, quad = lane >> 4;

  // B-frags (Q), 2 q-subtiles: qf[t][h][j] = Q[h*32+quad*8+j][q0+t*16+l16]
  short8 qf[2][2];
  #pragma unroll
  for (int t = 0; t < 2; t++)
    #pragma unroll
    for (int h = 0; h < 2; h++)
      #pragma unroll
      for (int j = 0; j < 8; j++)
        ((short*)&qf[t][h])[j] =
            *(const short*)&Qp[(size_t)(h * 32 + quad * 8 + j) * 1024 + q0 + t * 16 + l16];

  float m_run[2] = {-1e30f, -1e30f}, l_run[2] = {0.f, 0.f};
  float4v oacc[2][4];
  #pragma unroll
  for (int t = 0; t < 2; t++)
    #pragma unroll
    for (int dt = 0; dt < 4; dt++) oacc[t][dt] = (float4v){0.f, 0.f, 0.f, 0.f};

  for (int mc = 0; mc < 8; mc++) {
    __syncthreads();
    const bf16* ksrc = KTp + (size_t)mc * 8192;
    #pragma unroll
    for (int it = 0; it < 4; it++) {
      int g = (it * 256 + tid) * 8;
      *(short8*)&Ks[g >> 6][g & 63] = *(const short8*)&ksrc[g];
    }
    #pragma unroll
    for (int it = 0; it < 4; it++) {
      int s = it * 256 + tid;
      int d = s >> 4, cg = (s & 15) * 8;
      *(short8*)&Vs[d][cg] = *(const short8*)&Vp[(size_t)d * 1024 + mc * 128 + cg];
    }
    __syncthreads();

    // S MFMAs: wave's 32 keys x 32 q
    float sc[2][2][4];                 // [key_sub][q_sub][r]
    #pragma unroll
    for (int s = 0; s < 2; s++) {
      int st = wave * 2 + s;
      short8 af0 = *(const short8*)&Ks[st * 16 + l16][quad * 8];
      short8 af1 = *(const short8*)&Ks[st * 16 + l16][32 + quad * 8];
      #pragma unroll
      for (int t = 0; t < 2; t++) {
        float4v a = (float4v){0.f, 0.f, 0.f, 0.f};
        a = __builtin_amdgcn_mfma_f32_16x16x32_bf16(af0, qf[t][0], a, 0, 0, 0);
        a = __builtin_amdgcn_mfma_f32_16x16x32_bf16(af1, qf[t][1], a, 0, 0, 0);
        #pragma unroll
        for (int r = 0; r < 4; r++) sc[s][t][r] = a[r] * 0.125f;
      }
    }

    // online softmax per q-subtile
    float alpha[2], pf[2][2][4];
    #pragma unroll
    for (int t = 0; t < 2; t++) {
      float cmax = sc[0][t][0];
      #pragma unroll
      for (int s = 0; s < 2; s++)
        #pragma unroll
        for (int r = 0; r < 4; r++) cmax = fmaxf(cmax, sc[s][t][r]);
      cmax = fmaxf(cmax, __shfl_xor(cmax, 16, 64));
      cmax = fmaxf(cmax, __shfl_xor(cmax, 32, 64));
      float mnew = fmaxf(m_run[t], cmax);
      alpha[t] = __expf(m_run[t] - mnew);
      float psum = 0.f;
      #pragma unroll
      for (int s = 0; s < 2; s++)
        #pragma unroll
        for (int r = 0; r < 4; r++) {
          pf[t][s][r] = __expf(sc[s][t][r] - mnew);
          psum += pf[t][s][r];
        }
      psum += __shfl_xor(psum, 16, 64);
      psum += __shfl_xor(psum, 32, 64);
      l_run[t] = l_run[t] * alpha[t] + psum;
      m_run[t] = mnew;
    }

    // P -> PV A-frag layout via shuffles (per q-subtile)
    short8 paf[2];
    #pragma unroll
    for (int t = 0; t < 2; t++)
      #pragma unroll
      for (int j = 0; j < 8; j++) {
        int p   = quad * 8 + j;
        int src = (((p >> 2) & 3) << 4) + l16;
        float v0 = __shfl(pf[t][0][j & 3], src, 64);
        float v1 = __shfl(pf[t][1][j & 3], src, 64);
        float v  = (quad < 2) ? v0 : v1;
        bf16 pb = __float2bfloat16(v);
        ((short*)&paf[t])[j] = *(short*)&pb;
      }
    float al[2][4];
    #pragma unroll
    for (int t = 0; t < 2; t++)
      #pragma unroll
      for (int r = 0; r < 4; r++) al[t][r] = __shfl(alpha[t], quad * 4 + r, 64);

    // PV MFMAs: Vs frags reused across both q-subtiles
    #pragma unroll
    for (int dt = 0; dt < 4; dt++) {
      short8 bfr = *(const short8*)&Vs[dt * 16 + l16][wave * 32 + quad * 8];
      #pragma unroll
      for (int t = 0; t < 2; t++) {
        float4v c;
        #pragma unroll
        for (int r = 0; r < 4; r++) c[r] = oacc[t][dt][r] * al[t][r];
        oacc[t][dt] = __builtin_amdgcn_mfma_f32_16x16x32_bf16(paf[t], bfr, c, 0, 0, 0);
      }
    }
  }

  // cross-wave combine
  __syncthreads();
  if (quad == 0) {
    #pragma unroll
    for (int t = 0; t < 2; t++) {
      mS[wave * 32 + t * 16 + l16] = m_run[t];
      lS[wave * 32 + t * 16 + l16] = l_run[t];
    }
  }
  #pragma unroll
  for (int t = 0; t < 2; t++)
    #pragma unroll
    for (int dt = 0; dt < 4; dt++)
      #pragma unroll
      for (int r = 0; r < 4; r++)
        Ow[wave * 2080 + (t * 16 + quad * 4 + r) * 65 + dt * 16 + l16] = oacc[t][dt][r];
  __syncthreads();

  bf16* op = oT + (size_t)zb * o_bstride;
  #pragma unroll
  for (int k = 0; k < 8; k++) {
    int idx = k * 256 + tid;
    int q = idx >> 6, d = idx & 63;
    float mstar = mS[q];
    #pragma unroll
    for (int w = 1; w < 4; w++) mstar = fmaxf(mstar, mS[w * 32 + q]);
    float num = 0.f, den = 0.f;
    #pragma unroll
    for (int w = 0; w < 4; w++) {
      float e = __expf(mS[w * 32 + q] - mstar);
      den += lS[w * 32 + q] * e;
      num += Ow[w * 2080 + q * 65 + d] * e;
    }
    op[(size_t)(q0 + q) * 256 + n * 64 + d] = __float2bfloat16(num / den);
  }
}

// proj GEMM on MFMA: out[b][m][l] = Pb[m][:]·o[:][l] + bproj[m] + x, f32 out.
__global__ __launch_bounds__(256) void gemm_proj_mfma(
    const bf16* __restrict__ Pb, const bf16* __restrict__ oT,
    const float* __restrict__ bproj, const float* __restrict__ x,
    float* __restrict__ out, int b_off, size_t o_bstride) {
  __shared__ bf16 As[128][40];
  __shared__ bf16 Bs[128][40];
  int zb = blockIdx.z, b = zb + b_off;
  int m0 = blockIdx.y * 128, l0 = blockIdx.x * 128;
  const bf16* ob = oT + (size_t)zb * o_bstride;
  int tid = threadIdx.x, lane = tid & 63, wave = tid >> 6;
  int l16 = lane & 15, quad = lane >> 4;
  int mi0 = (wave & 1) * 4, nj0 = (wave >> 1) * 4;
  float4v acc[4][4];
  #pragma unroll
  for (int i = 0; i < 4; i++)
    #pragma unroll
    for (int j = 0; j < 4; j++) acc[i][j] = (float4v){0.f, 0.f, 0.f, 0.f};

  for (int kc = 0; kc < 8; kc++) {
    __syncthreads();
    #pragma unroll
    for (int it = 0; it < 2; it++) {
      int s = it * 256 + tid;
      int mm = s >> 2, kk = (s & 3) * 8;
      *(short8*)&As[mm][kk] = *(const short8*)&Pb[(size_t)(m0 + mm) * 256 + kc * 32 + kk];
      *(short8*)&Bs[mm][kk] = *(const short8*)&ob[(size_t)(l0 + mm) * 256 + kc * 32 + kk];
    }
    __syncthreads();
    short8 af[4], bfr[4];
    #pragma unroll
    for (int i = 0; i < 4; i++) af[i]  = *(const short8*)&As[(mi0 + i) * 16 + l16][quad * 8];
    #pragma unroll
    for (int j = 0; j < 4; j++) bfr[j] = *(const short8*)&Bs[(nj0 + j) * 16 + l16][quad * 8];
    #pragma unroll
    for (int i = 0; i < 4; i++)
      #pragma unroll
      for (int j = 0; j < 4; j++)
        acc[i][j] = __builtin_amdgcn_mfma_f32_16x16x32_bf16(af[i], bfr[j], acc[i][j], 0, 0, 0);
  }

  #pragma unroll
  for (int i = 0; i < 4; i++) {
    #pragma unroll
    for (int r = 0; r < 4; r++) {
      int m = m0 + (mi0 + i) * 16 + quad * 4 + r;
      float bias = bproj[m];
      #pragma unroll
      for (int j = 0; j < 4; j++) {
        int l = l0 + (nj0 + j) * 16 + l16;
        size_t idx = (size_t)(b * 256 + m) * 1024 + l;
        out[idx] = acc[i][j][r] + bias + x[idx];
      }
    }
  }
}

extern "C" void kernel_launch(void* const* d_in, const int* in_sizes, int n_in,
                              void* d_out, int out_size, void* d_ws, size_t ws_size,
                              hipStream_t stream) {
  int ix = 0, iga = 1, ibe = 2, iwq = 3, ibq = 4, iwk = 5, ibk = 6,
      iwv = 7, ibv = 8, iwp = 9, ibp = 10;
  if (in_sizes[0] != 4194304) {
    if (in_sizes[10] == 4194304 && in_sizes[1] == 256) {
      ibe = 0; ibk = 1; ibp = 2; ibq = 3; ibv = 4; iga = 5;
      iwk = 6; iwp = 7; iwq = 8; iwv = 9; ix = 10;
    } else if (in_sizes[10] == 4194304 && in_sizes[1] == 65536) {
      ibp = 0; iwp = 1; ibv = 2; iwv = 3; ibk = 4; iwk = 5;
      ibq = 6; iwq = 7; ibe = 8; iga = 9; ix = 10;
    } else {
      for (int i = 0; i < 11; i++) if (in_sizes[i] == 4194304) ix = i;
    }
  }
  const float* x     = (const float*)d_in[ix];
  const float* gamma = (const float*)d_in[iga];
  const float* beta  = (const float*)d_in[ibe];
  const float* wq    = (const float*)d_in[iwq];
  const float* bq    = (const float*)d_in[ibq];
  const float* wk    = (const float*)d_in[iwk];
  const float* bk    = (const float*)d_in[ibk];
  const float* wv    = (const float*)d_in[iwv];
  const float* bv    = (const float*)d_in[ibv];
  const float* wproj = (const float*)d_in[iwp];
  const float* bproj = (const float*)d_in[ibp];
  float* out = (float*)d_out;

  const size_t QKV_B = (size_t)768 * 1024;
  const size_t O_B   = (size_t)256 * 1024;
  char* wsp = (char*)d_ws;
  float2* stats = (float2*)wsp;                        // 4 KB
  bf16* Wb = (bf16*)(wsp + 8192);                      // 384 KB
  bf16* Pb = (bf16*)(wsp + 8192 + 393216);             // 128 KB
  const size_t HT0 = 8192 + 393216 + 131072;
  size_t full_need = HT0 + (size_t)16 * O_B * 2 + (size_t)16 * QKV_B * 2; // ~34.1 MB

  stats_kernel<<<512, 256, 0, stream>>>(x, stats);
  wpack<<<1024, 256, 0, stream>>>(wq, wk, wv, wproj, Wb, Pb);

  if (ws_size >= full_need) {
    bf16* hT  = (bf16*)(wsp + HT0);                    // 8 MB; reused as oT
    bf16* qkv = (bf16*)(wsp + HT0 + 16 * O_B * 2);     // 24 MB
    bf16* oT  = hT;
    gnt_kernel   <<<dim3(16, 4, 16), 256, 0, stream>>>(x, gamma, beta, stats, hT, 0);
    gemm_qkv_mfma<<<dim3(8, 6, 16), 256, 0, stream>>>(hT, Wb, bq, bk, bv, qkv, QKV_B);
    attn_kernel  <<<dim3(32, 4, 16), 256, 0, stream>>>(qkv, oT, QKV_B, O_B);
    gemm_proj_mfma<<<dim3(8, 2, 16), 256, 0, stream>>>(Pb, oT, bproj, x, out, 0, O_B);
  } else {
    bf16* hT  = (bf16*)(wsp + HT0);
    bf16* qkv = (bf16*)(wsp + HT0 + O_B * 2);
    bf16* oT  = hT;
    for (int b = 0; b < 16; b++) {
      gnt_kernel   <<<dim3(16, 4, 1), 256, 0, stream>>>(x, gamma, beta, stats, hT, b);
      gemm_qkv_mfma<<<dim3(8, 6, 1), 256, 0, stream>>>(hT, Wb, bq, bk, bv, qkv, 0);
      attn_kernel  <<<dim3(32, 4, 1), 256, 0, stream>>>(qkv, oT, 0, 0);
      gemm_proj_mfma<<<dim3(8, 2, 1), 256, 0, stream>>>(Pb, oT, bproj, x, out, b, 0);
    }
  }
}